// Round 13
// baseline (283.505 us; speedup 1.0000x reference)
//
#include <hip/hip_runtime.h>
#include <math.h>

// PLDA pairwise scorer, eigendecomposition-free, all-symmetric formulation.
// Z = S_wn^{-1/2} via degree-4 Chebyshev in P = S_wn - I; M = Z*SB*Z;
// F = f0(inv_s*M) via degree-19 base-4 bivariate Chebyshev
// (F = G0 + T4*G1 + T8*G2 + T12*G3 + T16*G4); B = (63/64)*inv_s*Z*F*Z.
// out = 2 v_i^T B v_j - q_i - q_j - log_div.
// Strip-chaining; elementwise-full-matrix-in-LDS fusion for Z and T2;
// nontemporal stores for the 268 MB output. 12 dispatches.

#define D 128
#define NCLS 256
#define NPC 64
#define MTEST 8192
#define COUNT (NCLS*NPC)

// ws float-offset layout
#define fMC    0
#define fMEAN  16384
#define fSCAL  16640
#define fMAT   32768
#define fSWRAW 442368
#define fPART  458752
#define fU     458752
#define fV     983040
#define fQ     1507328
#define fBBF   1515520

// matrix slots
#define sP   0
#define sSB  1
#define sP2  2
#define sP3  3
#define sP4  4
#define sZ   5
#define sMm  7
#define sC2  8
#define sXH  10
#define sT2  11
#define sT3  12
#define sT4  13
#define sT8  14
#define sT12 15
#define sT16 16
#define sG0  18   // G0..G4 = 18..22
#define sF   23

using short8 = __attribute__((ext_vector_type(8))) short;
using f32x4  = __attribute__((ext_vector_type(4))) float;

__device__ inline unsigned short f2bf(float f) {
  unsigned u = __float_as_uint(f);
  unsigned r = u + 0x7FFFu + ((u >> 16) & 1u);
  return (unsigned short)(r >> 16);
}
__device__ inline float bf2f(unsigned short h) {
  return __uint_as_float(((unsigned)h) << 16);
}
__device__ inline float valU(const unsigned short* m, int idx) {
  return bf2f(m[idx]) + bf2f(m[idx + 16384]);
}
__device__ inline void storeDual(unsigned short* m, int idx, float g) {
  unsigned short hb = f2bf(g);
  m[idx] = hb;
  m[16384 + idx] = f2bf(g - bf2f(hb));
}
__device__ inline unsigned short* MS(float* ws, int m) {
  return (unsigned short*)(ws + fMAT) + (size_t)m * 32768;
}
// 32-row LDS strip, dual plane (+4096 ushorts), XOR-swizzled rows
__device__ inline short8 st8(const unsigned short* L, int rloc, int colk) {
  unsigned u = ((unsigned)(rloc * 128 + colk)) ^ (((unsigned)(rloc & 7)) << 3);
  return *(const short8*)(L + u);
}
__device__ inline float stValU(const unsigned short* L, int rloc, int col) {
  unsigned u = ((unsigned)(rloc * 128 + col)) ^ (((unsigned)(rloc & 7)) << 3);
  return bf2f(L[u]) + bf2f(L[4096 + u]);
}
__device__ inline void stPutDual(unsigned short* L, int rloc, int col, float g) {
  unsigned u = ((unsigned)(rloc * 128 + col)) ^ (((unsigned)(rloc & 7)) << 3);
  unsigned short hb = f2bf(g);
  L[u] = hb;
  L[4096 + u] = f2bf(g - bf2f(hb));
}
// full 128x128 LDS dual matrix (plane stride 16384 ushorts), swizzled
__device__ inline short8 lf8(const unsigned short* L, int row, int colk) {
  unsigned u = ((unsigned)(row * 128 + colk)) ^ (((unsigned)(row & 7)) << 3);
  return *(const short8*)(L + u);
}
__device__ inline void lfPutDual(unsigned short* L, int row, int col, float g) {
  unsigned u = ((unsigned)(row * 128 + col)) ^ (((unsigned)(row & 7)) << 3);
  unsigned short hb = f2bf(g);
  L[u] = hb;
  L[16384 + u] = f2bf(g - bf2f(hb));
}

// 16x16 tile, K=128: A global rows x B global (symmetric)
__device__ __forceinline__ f32x4 tile_AB(const unsigned short* __restrict__ A, int rA,
                                         const unsigned short* __restrict__ B, int cB,
                                         int lane, f32x4 acc) {
  #pragma unroll
  for (int ks = 0; ks < 4; ks++) {
    int kb = ks * 32 + (lane >> 4) * 8;
    short8 ah = *(const short8*)(A + rA * 128 + kb);
    short8 al = *(const short8*)(A + 16384 + rA * 128 + kb);
    short8 bh = *(const short8*)(B + cB * 128 + kb);
    short8 bl = *(const short8*)(B + 16384 + cB * 128 + kb);
    acc = __builtin_amdgcn_mfma_f32_16x16x32_bf16(ah, bh, acc, 0, 0, 0);
    acc = __builtin_amdgcn_mfma_f32_16x16x32_bf16(al, bh, acc, 0, 0, 0);
    acc = __builtin_amdgcn_mfma_f32_16x16x32_bf16(ah, bl, acc, 0, 0, 0);
  }
  return acc;
}
// A LDS strip x B global
__device__ __forceinline__ f32x4 tile_LB(const unsigned short* __restrict__ L, int rloc,
                                         const unsigned short* __restrict__ B, int cB,
                                         int lane, f32x4 acc) {
  #pragma unroll
  for (int ks = 0; ks < 4; ks++) {
    int kb = ks * 32 + (lane >> 4) * 8;
    short8 ah = st8(L, rloc, kb);
    short8 al = st8(L + 4096, rloc, kb);
    short8 bh = *(const short8*)(B + cB * 128 + kb);
    short8 bl = *(const short8*)(B + 16384 + cB * 128 + kb);
    acc = __builtin_amdgcn_mfma_f32_16x16x32_bf16(ah, bh, acc, 0, 0, 0);
    acc = __builtin_amdgcn_mfma_f32_16x16x32_bf16(al, bh, acc, 0, 0, 0);
    acc = __builtin_amdgcn_mfma_f32_16x16x32_bf16(ah, bl, acc, 0, 0, 0);
  }
  return acc;
}
// A LDS-full rows x B global
__device__ __forceinline__ f32x4 tile_FG(const unsigned short* __restrict__ Lf, int rA,
                                         const unsigned short* __restrict__ B, int cB,
                                         int lane, f32x4 acc) {
  #pragma unroll
  for (int ks = 0; ks < 4; ks++) {
    int kb = ks * 32 + (lane >> 4) * 8;
    short8 ah = lf8(Lf, rA, kb);
    short8 al = lf8(Lf + 16384, rA, kb);
    short8 bh = *(const short8*)(B + cB * 128 + kb);
    short8 bl = *(const short8*)(B + 16384 + cB * 128 + kb);
    acc = __builtin_amdgcn_mfma_f32_16x16x32_bf16(ah, bh, acc, 0, 0, 0);
    acc = __builtin_amdgcn_mfma_f32_16x16x32_bf16(al, bh, acc, 0, 0, 0);
    acc = __builtin_amdgcn_mfma_f32_16x16x32_bf16(ah, bl, acc, 0, 0, 0);
  }
  return acc;
}
// A LDS strip x B LDS-full
__device__ __forceinline__ f32x4 tile_SF(const unsigned short* __restrict__ Ls, int rloc,
                                         const unsigned short* __restrict__ Lf, int cB,
                                         int lane, f32x4 acc) {
  #pragma unroll
  for (int ks = 0; ks < 4; ks++) {
    int kb = ks * 32 + (lane >> 4) * 8;
    short8 ah = st8(Ls, rloc, kb);
    short8 al = st8(Ls + 4096, rloc, kb);
    short8 bh = lf8(Lf, cB, kb);
    short8 bl = lf8(Lf + 16384, cB, kb);
    acc = __builtin_amdgcn_mfma_f32_16x16x32_bf16(ah, bh, acc, 0, 0, 0);
    acc = __builtin_amdgcn_mfma_f32_16x16x32_bf16(al, bh, acc, 0, 0, 0);
    acc = __builtin_amdgcn_mfma_f32_16x16x32_bf16(ah, bl, acc, 0, 0, 0);
  }
  return acc;
}
// A LDS-full rows x B LDS-full
__device__ __forceinline__ f32x4 tile_FF(const unsigned short* __restrict__ Lf, int rA,
                                         int cB, int lane, f32x4 acc) {
  #pragma unroll
  for (int ks = 0; ks < 4; ks++) {
    int kb = ks * 32 + (lane >> 4) * 8;
    short8 ah = lf8(Lf, rA, kb);
    short8 al = lf8(Lf + 16384, rA, kb);
    short8 bh = lf8(Lf, cB, kb);
    short8 bl = lf8(Lf + 16384, cB, kb);
    acc = __builtin_amdgcn_mfma_f32_16x16x32_bf16(ah, bh, acc, 0, 0, 0);
    acc = __builtin_amdgcn_mfma_f32_16x16x32_bf16(al, bh, acc, 0, 0, 0);
    acc = __builtin_amdgcn_mfma_f32_16x16x32_bf16(ah, bl, acc, 0, 0, 0);
  }
  return acc;
}

// ---------------- K1: Gram partials + class means ----------------
__global__ __launch_bounds__(256) void k_gt_partial(const float* __restrict__ X, float* __restrict__ ws) {
  __shared__ unsigned short xt[128 * 256];
  int b = blockIdx.x, tid = threadIdx.x;
  const float* Xc = X + b * 256 * D;
  for (int idx = tid; idx < 256 * D; idx += 256) {
    int s = idx >> 7, d = idx & 127;
    unsigned byte = ((unsigned)(d * 512 + s * 2)) ^ (((unsigned)(d & 7)) << 4);
    *(unsigned short*)((char*)xt + byte) = f2bf(Xc[idx]);
  }
  {
    int d = tid & 127;
    for (int cc = (tid >> 7); cc < 4; cc += 2) {
      const float* p = Xc + cc * 64 * D + d;
      float s = 0.f;
      #pragma unroll
      for (int n = 0; n < 64; n++) s += p[n * D];
      ((unsigned short*)ws)[d * 256 + (b * 4 + cc)] = f2bf(s * (1.0f / 64.0f));
    }
  }
  __syncthreads();
  int w = tid >> 6, lane = tid & 63;
  int wr = (w >> 1) * 64, wc = (w & 1) * 64;
  f32x4 acc[4][4] = {};
  for (int ks = 0; ks < 8; ks++) {
    int kb = ks * 32 + (lane >> 4) * 8;
    short8 af[4];
    #pragma unroll
    for (int mt = 0; mt < 4; mt++) {
      int r = wr + mt * 16 + (lane & 15);
      unsigned byte = ((unsigned)(r * 512 + kb * 2)) ^ (((unsigned)(r & 7)) << 4);
      af[mt] = *(short8*)((char*)xt + byte);
    }
    #pragma unroll
    for (int nt = 0; nt < 4; nt++) {
      int c = wc + nt * 16 + (lane & 15);
      unsigned byte = ((unsigned)(c * 512 + kb * 2)) ^ (((unsigned)(c & 7)) << 4);
      short8 bfr = *(short8*)((char*)xt + byte);
      #pragma unroll
      for (int mt = 0; mt < 4; mt++)
        acc[mt][nt] = __builtin_amdgcn_mfma_f32_16x16x32_bf16(af[mt], bfr, acc[mt][nt], 0, 0, 0);
    }
  }
  float* outp = ws + fPART + b * 16384;
  #pragma unroll
  for (int mt = 0; mt < 4; mt++)
    #pragma unroll
    for (int nt = 0; nt < 4; nt++)
      #pragma unroll
      for (int r = 0; r < 4; r++) {
        int row = wr + mt * 16 + (lane >> 4) * 4 + r;
        int col = wc + nt * 16 + (lane & 15);
        outp[row * 128 + col] = acc[mt][nt][r];
      }
}

// ---------------- K2: reduce partials; blk0: mean; blk1: inv_s ----------------
__global__ void k_reduce(float* __restrict__ ws) {
  __shared__ float red2[4];
  int tid = threadIdx.x;
  int idx = blockIdx.x * 256 + tid;
  const float* part = ws + fPART;
  float s = 0.f;
  #pragma unroll 8
  for (int p = 0; p < 64; p++) s += part[p * 16384 + idx];
  ws[fSWRAW + idx] = s;
  if (blockIdx.x == 0 && tid < 128) {
    const unsigned short* McT = (const unsigned short*)ws;
    float m = 0.f;
    for (int k = 0; k < 256; k++) m += bf2f(McT[tid * 256 + k]);
    ws[fMEAN + tid] = m * (1.0f / 256.0f);
  }
  if (blockIdx.x == 1) {
    float v = 0.f;
    if (tid < 128) {
      float gdd = 0.f;
      for (int p = 0; p < 64; p++) gdd += part[p * 16384 + tid * 129];
      const unsigned short* McT = (const unsigned short*)ws;
      float nrm = 0.f;
      for (int k = 0; k < 256; k++) { float x = bf2f(McT[tid * 256 + k]); nrm += x * x; }
      v = gdd * (1.0f / COUNT) - nrm * (1.0f / 256.0f);
    }
    #pragma unroll
    for (int off = 32; off > 0; off >>= 1) v += __shfl_down(v, off);
    if ((tid & 63) == 0) red2[tid >> 6] = v;
    __syncthreads();
    if (tid == 0) {
      float inv_s = 128.0f / (red2[0] + red2[1] + red2[2] + red2[3]);
      ws[fSCAL + 1] = inv_s;
      ws[fSCAL + 7] = 0.984375f * inv_s;
    }
  }
}

// ---------------- K3: SB strip (K=256) + P strip ----------------
__global__ __launch_bounds__(1024) void k_sbp(float* __restrict__ ws) {
  const unsigned short* Mc = (const unsigned short*)ws;
  const float* mv = ws + fMEAN;
  const float* swraw = ws + fSWRAW;
  float inv_s = ws[fSCAL + 1];
  unsigned short* SB = MS(ws, sSB);
  unsigned short* P = MS(ws, sP);
  int tid = threadIdx.x, b = blockIdx.x;
  int w = tid >> 6, lane = tid & 63;
  int wr = (w & 1) * 16, wc = (w >> 1) * 16;
  int brow = b * 32;
  f32x4 acc = {};
  for (int ks = 0; ks < 8; ks++) {
    int kb = ks * 32 + (lane >> 4) * 8;
    short8 af = *(const short8*)(Mc + (brow + wr + (lane & 15)) * 256 + kb);
    short8 bf = *(const short8*)(Mc + (wc + (lane & 15)) * 256 + kb);
    acc = __builtin_amdgcn_mfma_f32_16x16x32_bf16(af, bf, acc, 0, 0, 0);
  }
  #pragma unroll
  for (int r = 0; r < 4; r++) {
    int row = brow + wr + (lane >> 4) * 4 + r;
    int col = wc + (lane & 15);
    int idx = row * 128 + col;
    float g = acc[r] * (1.0f / 256.0f) - mv[row] * mv[col];
    storeDual(SB, idx, g);
    float s = (swraw[idx] * (1.0f / COUNT) - g - mv[row] * mv[col]) * inv_s;
    storeDual(P, idx, s - ((row == col) ? 1.0f : 0.0f));
  }
}

// ---------------- K4: strips P2 -> P3 -> P4 (+tr P^4); blocks>=4: V ----------------
__global__ __launch_bounds__(1024) void k_pows(const float* __restrict__ test, float* __restrict__ ws) {
  __shared__ unsigned short sA[8192];
  __shared__ unsigned short sB[8192];
  __shared__ float red[16];
  float* scal = ws + fSCAL;
  int tid = threadIdx.x, b = blockIdx.x;
  if (b >= 4) {
    unsigned short* Vbf = (unsigned short*)(ws + fV);
    const float* mv = ws + fMEAN;
    int base = (b - 4) * 32768;
    #pragma unroll 4
    for (int k = 0; k < 32; k++) {
      int idx = base + k * 1024 + tid;
      Vbf[idx] = f2bf(test[idx] - mv[idx & 127]);
    }
    return;
  }
  const unsigned short* P = MS(ws, sP);
  unsigned short* P2 = MS(ws, sP2);
  unsigned short* P3 = MS(ws, sP3);
  unsigned short* P4 = MS(ws, sP4);
  int w = tid >> 6, lane = tid & 63;
  int wr = (w & 1) * 16, wc = (w >> 1) * 16;
  int brow = b * 32;
  float tsum = 0.f;
  {
    f32x4 acc = {};
    acc = tile_AB(P, brow + wr + (lane & 15), P, wc + (lane & 15), lane, acc);
    #pragma unroll
    for (int r = 0; r < 4; r++) {
      int rloc = wr + (lane >> 4) * 4 + r;
      int col = wc + (lane & 15);
      float g = acc[r];
      stPutDual(sA, rloc, col, g);
      storeDual(P2, (brow + rloc) * 128 + col, g);
      tsum += g * g;
    }
  }
  #pragma unroll
  for (int off = 32; off > 0; off >>= 1) tsum += __shfl_down(tsum, off);
  if (lane == 0) red[w] = tsum;
  __syncthreads();
  if (tid == 0) {
    float s = 0.f;
    #pragma unroll
    for (int i = 0; i < 16; i++) s += red[i];
    scal[60 + b] = s;
  }
  {
    f32x4 acc = {};
    acc = tile_LB(sA, wr + (lane & 15), P, wc + (lane & 15), lane, acc);
    #pragma unroll
    for (int r = 0; r < 4; r++) {
      int rloc = wr + (lane >> 4) * 4 + r;
      int col = wc + (lane & 15);
      stPutDual(sB, rloc, col, acc[r]);
      storeDual(P3, (brow + rloc) * 128 + col, acc[r]);
    }
  }
  __syncthreads();
  {
    f32x4 acc = {};
    acc = tile_LB(sB, wr + (lane & 15), P, wc + (lane & 15), lane, acc);
    #pragma unroll
    for (int r = 0; r < 4; r++) {
      int rloc = wr + (lane >> 4) * 4 + r;
      int col = wc + (lane & 15);
      storeDual(P4, (brow + rloc) * 128 + col, acc[r]);
    }
  }
}

// ---------------- K5: full Z in LDS (elementwise) -> M1 strip -> Mm strip ----------------
__global__ __launch_bounds__(1024) void k_zm(float* __restrict__ ws) {
  __shared__ unsigned short shZ[32768];  // full Z dual, 64 KB
  __shared__ unsigned short shA[8192];   // M1 strip dual, 16 KB
  __shared__ float cj[5];
  __shared__ float bt[5];
  float* scal = ws + fSCAL;
  int tid = threadIdx.x, b = blockIdx.x;
  float trP4 = scal[60] + scal[61] + scal[62] + scal[63];
  float a = 1.05f * sqrtf(sqrtf(fmaxf(trP4, 1e-30f)));
  a = fminf(fmaxf(a, 1e-3f), 0.95f);
  if (tid < 5) {
    const float PI = 3.14159265358979f;
    float s = 0.f;
    for (int i = 0; i < 64; i++) {
      float th = (i + 0.5f) * (PI / 64.0f);
      float x = cosf(th);
      s += (1.0f / sqrtf(1.0f + a * x)) * cosf((float)tid * th);
    }
    cj[tid] = s * (2.0f / 64.0f);
  }
  __syncthreads();
  if (tid == 0) {
    float c0h = 0.5f * cj[0];
    float m0 = c0h - cj[2] + cj[4];
    float m1 = cj[1] - 3.0f * cj[3];
    float m2 = 2.0f * cj[2] - 8.0f * cj[4];
    float m3 = 4.0f * cj[3];
    float m4 = 8.0f * cj[4];
    float ia = 1.0f / a, p = 1.f;
    bt[0] = m0;
    p *= ia; bt[1] = m1 * p;
    p *= ia; bt[2] = m2 * p;
    p *= ia; bt[3] = m3 * p;
    p *= ia; bt[4] = m4 * p;
  }
  __syncthreads();
  const unsigned short *P = MS(ws, sP), *P2 = MS(ws, sP2),
    *P3 = MS(ws, sP3), *P4 = MS(ws, sP4);
  unsigned short* Zg = MS(ws, sZ);
  float b0 = bt[0], b1 = bt[1], b2 = bt[2], b3 = bt[3], b4 = bt[4];
  for (int idx = tid; idx < 16384; idx += 1024) {
    int row = idx >> 7, col = idx & 127;
    float dg = (row == col) ? 1.0f : 0.0f;
    float z = b0 * dg + b1 * valU(P, idx) + b2 * valU(P2, idx) +
              b3 * valU(P3, idx) + b4 * valU(P4, idx);
    lfPutDual(shZ, row, col, z);
    if ((row >> 5) == b) storeDual(Zg, idx, z);
  }
  __syncthreads();
  const unsigned short* SB = MS(ws, sSB);
  unsigned short* Mm = MS(ws, sMm);
  int w = tid >> 6, lane = tid & 63;
  int wr = (w & 1) * 16, wc = (w >> 1) * 16;
  int brow = b * 32;
  {
    f32x4 acc = {};
    acc = tile_FG(shZ, brow + wr + (lane & 15), SB, wc + (lane & 15), lane, acc);
    #pragma unroll
    for (int r = 0; r < 4; r++)
      stPutDual(shA, wr + (lane >> 4) * 4 + r, wc + (lane & 15), acc[r]);
  }
  __syncthreads();
  {
    f32x4 acc = {};
    acc = tile_SF(shA, wr + (lane & 15), shZ, wc + (lane & 15), lane, acc);
    #pragma unroll
    for (int r = 0; r < 4; r++) {
      int rloc = wr + (lane >> 4) * 4 + r;
      storeDual(Mm, (brow + rloc) * 128 + wc + (lane & 15), acc[r]);
    }
  }
}

// ---------------- K6: C2 strip (+tr M^4 partial) ----------------
__global__ __launch_bounds__(1024) void k_c2(float* __restrict__ ws) {
  __shared__ float red[16];
  float* scal = ws + fSCAL;
  const unsigned short* Mm = MS(ws, sMm);
  unsigned short* C2 = MS(ws, sC2);
  int tid = threadIdx.x, b = blockIdx.x;
  int w = tid >> 6, lane = tid & 63;
  int wr = (w & 1) * 16, wc = (w >> 1) * 16;
  int brow = b * 32;
  f32x4 acc = {};
  acc = tile_AB(Mm, brow + wr + (lane & 15), Mm, wc + (lane & 15), lane, acc);
  float tsum = 0.f;
  #pragma unroll
  for (int r = 0; r < 4; r++) {
    int rloc = wr + (lane >> 4) * 4 + r;
    float g = acc[r];
    storeDual(C2, (brow + rloc) * 128 + wc + (lane & 15), g);
    tsum += g * g;
  }
  #pragma unroll
  for (int off = 32; off > 0; off >>= 1) tsum += __shfl_down(tsum, off);
  if (lane == 0) red[w] = tsum;
  __syncthreads();
  if (tid == 0) {
    float s = 0.f;
    #pragma unroll
    for (int i = 0; i < 16; i++) s += red[i];
    scal[68 + b] = s;
  }
}

// interval from tr M^4 = ||C2||_F^2
__device__ inline void interval_cs(const float* scal, float* c0o, float* iho) {
  float trM4 = scal[68] + scal[69] + scal[70] + scal[71];
  float Lam = 1.03f * sqrtf(sqrtf(fmaxf(trM4, 1e-37f)));
  float lo = -0.02f * Lam, hi = Lam;
  *c0o = 0.5f * (hi + lo);
  *iho = 1.0f / (0.5f * (hi - lo));
}

// ---------------- K7: full T2 in LDS; blk 0-3: XH strip + T3; blk 4-7: T4 ----------------
__global__ __launch_bounds__(1024) void k_t34(float* __restrict__ ws) {
  __shared__ unsigned short shT2[32768]; // full T2 dual
  __shared__ unsigned short shXH[8192];  // XH strip dual (blocks 0-3)
  __shared__ float cs[2];
  float* scal = ws + fSCAL;
  int tid = threadIdx.x, b = blockIdx.x;
  if (tid == 0) {
    float c0, ih;
    interval_cs(scal, &c0, &ih);
    cs[0] = c0; cs[1] = ih;
  }
  __syncthreads();
  float c0 = cs[0], ih = cs[1];
  float a2 = 2.0f * ih * ih, b2c = -4.0f * c0 * ih * ih, g2 = 2.0f * c0 * c0 * ih * ih - 1.0f;
  const unsigned short* Mm = MS(ws, sMm);
  const unsigned short* C2 = MS(ws, sC2);
  unsigned short* T2g = MS(ws, sT2);
  unsigned short* XHg = MS(ws, sXH);
  bool isT3 = (b < 4);
  int bs = isT3 ? b : (b - 4);
  int brow = bs * 32;
  for (int idx = tid; idx < 16384; idx += 1024) {
    int row = idx >> 7, col = idx & 127;
    float m = valU(Mm, idx), c2v = valU(C2, idx);
    float dg = (row == col) ? 1.0f : 0.0f;
    float t2 = a2 * c2v + b2c * m + g2 * dg;
    lfPutDual(shT2, row, col, t2);
    if (!isT3 && (row >> 5) == bs) storeDual(T2g, idx, t2);
  }
  if (isT3) {
    for (int idx = tid; idx < 4096; idx += 1024) {
      int rloc = idx >> 7, col = idx & 127;
      int row = brow + rloc;
      int gidx = row * 128 + col;
      float m = valU(Mm, gidx);
      float xh = ih * m - ih * c0 * ((row == col) ? 1.0f : 0.0f);
      stPutDual(shXH, rloc, col, xh);
      storeDual(XHg, gidx, xh);
    }
  }
  __syncthreads();
  int w = tid >> 6, lane = tid & 63;
  int wr = (w & 1) * 16, wc = (w >> 1) * 16;
  if (isT3) {
    f32x4 acc = {};
    acc = tile_SF(shXH, wr + (lane & 15), shT2, wc + (lane & 15), lane, acc);
    unsigned short* T3 = MS(ws, sT3);
    #pragma unroll
    for (int r = 0; r < 4; r++) {
      int rloc = wr + (lane >> 4) * 4 + r;
      int col = wc + (lane & 15);
      storeDual(T3, (brow + rloc) * 128 + col, 2.0f * acc[r] - stValU(shXH, rloc, col));
    }
  } else {
    f32x4 acc = {};
    acc = tile_FF(shT2, brow + wr + (lane & 15), wc + (lane & 15), lane, acc);
    unsigned short* T4 = MS(ws, sT4);
    #pragma unroll
    for (int r = 0; r < 4; r++) {
      int row = brow + wr + (lane >> 4) * 4 + r;
      int col = wc + (lane & 15);
      storeDual(T4, row * 128 + col, 2.0f * acc[r] - ((row == col) ? 1.0f : 0.0f));
    }
  }
}

// ---------------- K8: blk 0-3: T8 -> T12 -> T16 strips; blk 4-19: G0..G4 ----------------
__global__ __launch_bounds__(1024) void k_t8g(float* __restrict__ ws) {
  __shared__ unsigned short sA[8192];
  __shared__ unsigned short sB[8192];
  __shared__ float cs[4];
  __shared__ float sat[20];
  __shared__ float sc[20];
  float* scal = ws + fSCAL;
  int tid = threadIdx.x;
  const unsigned short* T4 = MS(ws, sT4);
  if (blockIdx.x < 4) {
    int b = blockIdx.x, brow = b * 32;
    int w = tid >> 6, lane = tid & 63;
    int wr = (w & 1) * 16, wc = (w >> 1) * 16;
    unsigned short* T8 = MS(ws, sT8);
    unsigned short* T12 = MS(ws, sT12);
    unsigned short* T16 = MS(ws, sT16);
    {
      f32x4 acc = {};
      acc = tile_AB(T4, brow + wr + (lane & 15), T4, wc + (lane & 15), lane, acc);
      #pragma unroll
      for (int r = 0; r < 4; r++) {
        int rloc = wr + (lane >> 4) * 4 + r;
        int row = brow + rloc, col = wc + (lane & 15);
        float g = 2.0f * acc[r] - ((row == col) ? 1.0f : 0.0f);
        stPutDual(sA, rloc, col, g);
        storeDual(T8, row * 128 + col, g);
      }
    }
    __syncthreads();
    {
      f32x4 acc = {};
      acc = tile_LB(sA, wr + (lane & 15), T4, wc + (lane & 15), lane, acc);
      #pragma unroll
      for (int r = 0; r < 4; r++) {
        int rloc = wr + (lane >> 4) * 4 + r;
        int col = wc + (lane & 15);
        int idx = (brow + rloc) * 128 + col;
        float g = 2.0f * acc[r] - valU(T4, idx);
        stPutDual(sB, rloc, col, g);
        storeDual(T12, idx, g);
      }
    }
    __syncthreads();
    {
      f32x4 acc = {};
      acc = tile_LB(sB, wr + (lane & 15), T4, wc + (lane & 15), lane, acc);
      #pragma unroll
      for (int r = 0; r < 4; r++) {
        int rloc = wr + (lane >> 4) * 4 + r;
        int col = wc + (lane & 15);
        float g = 2.0f * acc[r] - stValU(sA, rloc, col);
        storeDual(T16, (brow + rloc) * 128 + col, g);
      }
    }
    return;
  }
  if (tid == 0) {
    float c0, ih;
    interval_cs(scal, &c0, &ih);
    float inv_s = scal[1];
    float t0 = (1.0f / 63.0f) / inv_s;
    float x0 = fminf(fmaxf((t0 - c0) * ih, -1.0f), 1.0f);
    cs[0] = acosf(x0); cs[1] = x0;
    cs[2] = 0.984375f * inv_s / ih;
  }
  __syncthreads();
  if (tid <= 19) {
    float th = cs[0], x0 = cs[1], SCc = cs[2];
    const float PI = 3.14159265358979f;
    float v;
    if (tid == 0) v = 0.5f * SCc * (2.0f / PI) * (sinf(th) - x0 * th);
    else if (tid == 1) v = SCc * (2.0f / PI) * (0.5f * th + 0.25f * sinf(2.0f * th) - x0 * sinf(th));
    else {
      float fj = (float)tid;
      v = SCc * (2.0f / PI) *
          (0.5f * (sinf((fj + 1.0f) * th) / (fj + 1.0f) + sinf((fj - 1.0f) * th) / (fj - 1.0f))
           - x0 * sinf(fj * th) / fj);
    }
    sat[tid] = v;
    sc[tid] = 0.f;
  }
  __syncthreads();
  if (tid == 0) {
    for (int j = 19; j >= 4; --j) {
      int k = j >> 2, r = j & 3;
      float aj = sat[j];
      if (r == 0) sc[k * 4] += aj;
      else { sc[k * 4 + r] += 2.0f * aj; sat[4 * k - r] -= aj; }
    }
    for (int r = 0; r < 4; r++) sc[r] += sat[r];
  }
  __syncthreads();
  const unsigned short* XH = MS(ws, sXH);
  const unsigned short* T2 = MS(ws, sT2);
  const unsigned short* T3 = MS(ws, sT3);
  int idx = (blockIdx.x - 4) * 1024 + tid;
  {
    int row = idx >> 7, col = idx & 127;
    float dg = (row == col) ? 1.0f : 0.0f;
    float x1 = valU(XH, idx), x2 = valU(T2, idx), x3 = valU(T3, idx);
    #pragma unroll
    for (int k = 0; k < 5; k++) {
      float g = sc[k * 4 + 0] * dg + sc[k * 4 + 1] * x1 + sc[k * 4 + 2] * x2 +
                sc[k * 4 + 3] * x3;
      storeDual(MS(ws, sG0 + k), idx, g);
    }
  }
}

// ---------------- K9: F = G0 + T4 G1 + T8 G2 + T12 G3 + T16 G4 (+trF2) ----------------
__global__ __launch_bounds__(1024) void k_bigF(float* __restrict__ ws) {
  __shared__ float red[16];
  float* scal = ws + fSCAL;
  const unsigned short* G0 = MS(ws, sG0);
  unsigned short* Fm = MS(ws, sF);
  int tid = threadIdx.x, b = blockIdx.x;
  int w = tid >> 6, lane = tid & 63;
  int wr = (w & 1) * 16, wc = (w >> 1) * 16;
  int brow = b * 32;
  int rA = brow + wr + (lane & 15), cB = wc + (lane & 15);
  f32x4 acc = {};
  acc = tile_AB(MS(ws, sT4), rA, MS(ws, sG0 + 1), cB, lane, acc);
  acc = tile_AB(MS(ws, sT8), rA, MS(ws, sG0 + 2), cB, lane, acc);
  acc = tile_AB(MS(ws, sT12), rA, MS(ws, sG0 + 3), cB, lane, acc);
  acc = tile_AB(MS(ws, sT16), rA, MS(ws, sG0 + 4), cB, lane, acc);
  float tsum = 0.f;
  #pragma unroll
  for (int r = 0; r < 4; r++) {
    int rloc = wr + (lane >> 4) * 4 + r;
    int idx = (brow + rloc) * 128 + wc + (lane & 15);
    float g = acc[r] + valU(G0, idx);
    storeDual(Fm, idx, g);
    tsum += g * g;
  }
  #pragma unroll
  for (int off = 32; off > 0; off >>= 1) tsum += __shfl_down(tsum, off);
  if (lane == 0) red[w] = tsum;
  __syncthreads();
  if (tid == 0) {
    float s = 0.f;
    #pragma unroll
    for (int i = 0; i < 16; i++) s += red[i];
    scal[72 + b] = s;
  }
}

// ---------------- K10: A1 strip (LDS) -> Bbf strip ----------------
__global__ __launch_bounds__(1024) void k_b(float* __restrict__ ws) {
  __shared__ unsigned short sA[8192];
  const unsigned short* Z = MS(ws, sZ);
  const unsigned short* Fm = MS(ws, sF);
  unsigned short* Bbf = (unsigned short*)(ws + fBBF);
  float aeff = ws[fSCAL + 7];
  int tid = threadIdx.x, b = blockIdx.x;
  int w = tid >> 6, lane = tid & 63;
  int wr = (w & 1) * 16, wc = (w >> 1) * 16;
  int brow = b * 32;
  {
    f32x4 acc = {};
    acc = tile_AB(Z, brow + wr + (lane & 15), Fm, wc + (lane & 15), lane, acc);
    #pragma unroll
    for (int r = 0; r < 4; r++)
      stPutDual(sA, wr + (lane >> 4) * 4 + r, wc + (lane & 15), acc[r]);
  }
  __syncthreads();
  {
    f32x4 acc = {};
    acc = tile_LB(sA, wr + (lane & 15), Z, wc + (lane & 15), lane, acc);
    #pragma unroll
    for (int r = 0; r < 4; r++) {
      int rloc = wr + (lane >> 4) * 4 + r;
      Bbf[(brow + rloc) * 128 + wc + (lane & 15)] = f2bf(acc[r] * aeff);
    }
  }
}

// ---------------- K11: U = V*B; q; blk0: log_div ----------------
__global__ __launch_bounds__(256) void k_latent(float* __restrict__ ws) {
  __shared__ unsigned short vh[16384];
  __shared__ float qs[128];
  int blk = blockIdx.x, tid = threadIdx.x;
  if (blk == 0 && tid == 0) {
    float* scal = ws + fSCAL;
    float trF2 = fmaxf(scal[72] + scal[73] + scal[74] + scal[75], 1e-30f);
    scal[0] = 0.5f * (128.0f * 1.8378770664093453f + 0.5f * logf(trF2));
  }
  const unsigned short* Vbf = (const unsigned short*)(ws + fV);
  if (tid < 128) qs[tid] = 0.f;
  for (int idx = tid; idx < 16384; idx += 256) {
    int r = idx >> 7, c = idx & 127;
    unsigned short h = Vbf[blk * 16384 + idx];
    unsigned byte = ((unsigned)(r * 256 + c * 2)) ^ (((unsigned)(r & 7)) << 4);
    *(unsigned short*)((char*)vh + byte) = h;
  }
  __syncthreads();
  int w = tid >> 6, lane = tid & 63;
  int wr = (w >> 1) * 64, wc = (w & 1) * 64;
  const unsigned short* Bbf = (const unsigned short*)(ws + fBBF);
  f32x4 acc[4][4] = {};
  for (int ks = 0; ks < 4; ks++) {
    int kb = ks * 32 + (lane >> 4) * 8;
    short8 af[4], bfv[4];
    #pragma unroll
    for (int mt = 0; mt < 4; mt++) {
      int r = wr + mt * 16 + (lane & 15);
      unsigned byte = ((unsigned)(r * 256 + kb * 2)) ^ (((unsigned)(r & 7)) << 4);
      af[mt] = *(short8*)((char*)vh + byte);
    }
    #pragma unroll
    for (int nt = 0; nt < 4; nt++) {
      int c = wc + nt * 16 + (lane & 15);
      bfv[nt] = *(const short8*)(Bbf + c * 128 + kb);
    }
    #pragma unroll
    for (int mt = 0; mt < 4; mt++)
      #pragma unroll
      for (int nt = 0; nt < 4; nt++)
        acc[mt][nt] = __builtin_amdgcn_mfma_f32_16x16x32_bf16(af[mt], bfv[nt], acc[mt][nt], 0, 0, 0);
  }
  unsigned short* Ubf = (unsigned short*)(ws + fU);
  #pragma unroll
  for (int mt = 0; mt < 4; mt++)
    #pragma unroll
    for (int nt = 0; nt < 4; nt++)
      #pragma unroll
      for (int r = 0; r < 4; r++) {
        int row = wr + mt * 16 + (lane >> 4) * 4 + r;
        int col = wc + nt * 16 + (lane & 15);
        Ubf[(blk * 128 + row) * 128 + col] = f2bf(acc[mt][nt][r]);
      }
  #pragma unroll
  for (int mt = 0; mt < 4; mt++)
    #pragma unroll
    for (int r = 0; r < 4; r++) {
      int row = wr + mt * 16 + (lane >> 4) * 4 + r;
      float p = 0.f;
      #pragma unroll
      for (int nt = 0; nt < 4; nt++) {
        int col = wc + nt * 16 + (lane & 15);
        unsigned byte = ((unsigned)(row * 256 + col * 2)) ^ (((unsigned)(row & 7)) << 4);
        p += bf2f(f2bf(acc[mt][nt][r])) * bf2f(*(unsigned short*)((char*)vh + byte));
      }
      p += __shfl_xor(p, 1, 16);
      p += __shfl_xor(p, 2, 16);
      p += __shfl_xor(p, 4, 16);
      p += __shfl_xor(p, 8, 16);
      if ((lane & 15) == 0) atomicAdd(&qs[row], p);  // exactly 2 adds/row
    }
  __syncthreads();
  if (tid < 128) ws[fQ + blk * 128 + tid] = qs[tid];
}

// ---------------- K12: out = 2 U V^T - q_i - q_j - log_div (nontemporal) ----------------
__global__ __launch_bounds__(256) void k_pair(const float* __restrict__ ws, float* __restrict__ out) {
  __shared__ float qi[128];
  __shared__ float qj[128];
  __shared__ float sld;
  int bi = blockIdx.x, bj = blockIdx.y, tid = threadIdx.x;
  if (tid < 128) qi[tid] = ws[fQ + bi * 128 + tid];
  else qj[tid - 128] = ws[fQ + bj * 128 + (tid - 128)];
  if (tid == 0) sld = ws[fSCAL + 0];
  __syncthreads();
  int w = tid >> 6, lane = tid & 63;
  int wr = (w >> 1) * 64, wc = (w & 1) * 64;
  const unsigned short* Ubf = (const unsigned short*)(ws + fU);
  const unsigned short* Vbf = (const unsigned short*)(ws + fV);
  f32x4 acc[4][4] = {};
  for (int ks = 0; ks < 4; ks++) {
    int kb = ks * 32 + (lane >> 4) * 8;
    short8 af[4], bfv[4];
    #pragma unroll
    for (int mt = 0; mt < 4; mt++) {
      int r = bi * 128 + wr + mt * 16 + (lane & 15);
      af[mt] = *(const short8*)(Ubf + r * 128 + kb);
    }
    #pragma unroll
    for (int nt = 0; nt < 4; nt++) {
      int c = bj * 128 + wc + nt * 16 + (lane & 15);
      bfv[nt] = *(const short8*)(Vbf + c * 128 + kb);
    }
    #pragma unroll
    for (int mt = 0; mt < 4; mt++)
      #pragma unroll
      for (int nt = 0; nt < 4; nt++)
        acc[mt][nt] = __builtin_amdgcn_mfma_f32_16x16x32_bf16(af[mt], bfv[nt], acc[mt][nt], 0, 0, 0);
  }
  float ld = sld;
  #pragma unroll
  for (int mt = 0; mt < 4; mt++)
    #pragma unroll
    for (int nt = 0; nt < 4; nt++)
      #pragma unroll
      for (int r = 0; r < 4; r++) {
        int row = wr + mt * 16 + (lane >> 4) * 4 + r;
        int col = wc + nt * 16 + (lane & 15);
        float g = acc[mt][nt][r];
        float v = 2.0f * g - qi[row] - qj[col] - ld;
        __builtin_nontemporal_store(v,
          &out[(size_t)(bi * 128 + row) * MTEST + (bj * 128 + col)]);
      }
}

extern "C" void kernel_launch(void* const* d_in, const int* in_sizes, int n_in,
                              void* d_out, int out_size, void* d_ws, size_t ws_size,
                              hipStream_t stream) {
  (void)in_sizes; (void)n_in; (void)out_size; (void)ws_size;
  const float* X = (const float*)d_in[0];
  const float* test = (const float*)d_in[1];
  float* out = (float*)d_out;
  float* ws = (float*)d_ws;

  k_gt_partial<<<64, 256, 0, stream>>>(X, ws);
  k_reduce<<<64, 256, 0, stream>>>(ws);
  k_sbp<<<4, 1024, 0, stream>>>(ws);           // SB + P
  k_pows<<<36, 1024, 0, stream>>>(test, ws);   // P2->P3->P4 (+trP4) | V
  k_zm<<<4, 1024, 0, stream>>>(ws);            // Z (LDS full) -> M1 -> Mm
  k_c2<<<4, 1024, 0, stream>>>(ws);            // C2 (+trM4)
  k_t34<<<8, 1024, 0, stream>>>(ws);           // T2/XH (LDS) + T3 | T4
  k_t8g<<<20, 1024, 0, stream>>>(ws);          // T8->T12->T16 | G0..G4
  k_bigF<<<4, 1024, 0, stream>>>(ws);          // F (+trF2)
  k_b<<<4, 1024, 0, stream>>>(ws);             // A1 strip -> Bbf
  k_latent<<<64, 256, 0, stream>>>(ws);        // U, q
  k_pair<<<dim3(64, 64), 256, 0, stream>>>(ws, out);
}

// Round 14
// 272.017 us; speedup vs baseline: 1.0422x; 1.0422x over previous
//
#include <hip/hip_runtime.h>
#include <math.h>

// PLDA pairwise scorer, eigendecomposition-free, all-symmetric formulation.
// Z = S_wn^{-1/2} via degree-6 Chebyshev in P = S_wn - I; M = Z*SB*Z;
// F = f0(inv_s*M) via degree-24 bivariate Chebyshev
// (F = G0 + T5*G1 + T10*G2 + T15*G3 + T20*G4); B = (63/64)*inv_s*Z*F*Z.
// out = 2 v_i^T B v_j - q_i - q_j - log_div.
// Zero-redundancy strip-chaining (best-known config, R11 = 265 us) +
// nontemporal stores for the 268 MB output. 15 dispatches.

#define D 128
#define NCLS 256
#define NPC 64
#define MTEST 8192
#define COUNT (NCLS*NPC)

// ws float-offset layout
#define fMC    0
#define fMEAN  16384
#define fSCAL  16640
#define fMAT   32768
#define fSWRAW 442368
#define fPART  458752
#define fU     458752
#define fV     983040
#define fQ     1507328
#define fBBF   1515520

// matrix slots
#define sP   0
#define sSB  1
#define sP2  2
#define sP3  3
#define sP4  4
#define sZ   5
#define sMm  7
#define sC2  8
#define sXH  10
#define sT2  11
#define sT3  12
#define sT4  13
#define sT5  14
#define sT10 15
#define sT15 16
#define sT20 17
#define sG0  18   // G0..G4 = 18..22
#define sF   23

using short8 = __attribute__((ext_vector_type(8))) short;
using f32x4  = __attribute__((ext_vector_type(4))) float;

__device__ inline unsigned short f2bf(float f) {
  unsigned u = __float_as_uint(f);
  unsigned r = u + 0x7FFFu + ((u >> 16) & 1u);
  return (unsigned short)(r >> 16);
}
__device__ inline float bf2f(unsigned short h) {
  return __uint_as_float(((unsigned)h) << 16);
}
__device__ inline float valU(const unsigned short* m, int idx) {
  return bf2f(m[idx]) + bf2f(m[idx + 16384]);
}
__device__ inline void storeDual(unsigned short* m, int idx, float g) {
  unsigned short hb = f2bf(g);
  m[idx] = hb;
  m[16384 + idx] = f2bf(g - bf2f(hb));
}
__device__ inline unsigned short* MS(float* ws, int m) {
  return (unsigned short*)(ws + fMAT) + (size_t)m * 32768;
}
// 32-row LDS strip, dual plane (4096-ushort stride), XOR-swizzled rows
__device__ inline short8 st8(const unsigned short* L, int rloc, int colk) {
  unsigned u = ((unsigned)(rloc * 128 + colk)) ^ (((unsigned)(rloc & 7)) << 3);
  return *(const short8*)(L + u);
}
__device__ inline float stValU(const unsigned short* L, int rloc, int col) {
  unsigned u = ((unsigned)(rloc * 128 + col)) ^ (((unsigned)(rloc & 7)) << 3);
  return bf2f(L[u]) + bf2f(L[4096 + u]);
}
__device__ inline void stPutDual(unsigned short* L, int rloc, int col, float g) {
  unsigned u = ((unsigned)(rloc * 128 + col)) ^ (((unsigned)(rloc & 7)) << 3);
  unsigned short hb = f2bf(g);
  L[u] = hb;
  L[4096 + u] = f2bf(g - bf2f(hb));
}

// ---------------- generic strip matmul: C = alpha*(A x B) [+ beta*E1] [+ delta*I]
__device__ float mm_core(const unsigned short* A, const unsigned short* B,
                         unsigned short* C, const unsigned short* E1,
                         float alpha, float beta, float delta, int brow,
                         unsigned short* outBf, float aeff2) {
  int tid = threadIdx.x;
  int w = tid >> 6, lane = tid & 63;
  int wcol = w * 32;
  f32x4 acc[2][2] = {};
  #pragma unroll
  for (int ks = 0; ks < 4; ks++) {
    int kb = ks * 32 + (lane >> 4) * 8;
    short8 ah[2], al[2], bh[2], bl[2];
    #pragma unroll
    for (int mt = 0; mt < 2; mt++) {
      int r = brow + mt * 16 + (lane & 15);
      ah[mt] = *(const short8*)(A + r * 128 + kb);
      al[mt] = *(const short8*)(A + 16384 + r * 128 + kb);
    }
    #pragma unroll
    for (int nt = 0; nt < 2; nt++) {
      int c = wcol + nt * 16 + (lane & 15);
      bh[nt] = *(const short8*)(B + c * 128 + kb);
      bl[nt] = *(const short8*)(B + 16384 + c * 128 + kb);
    }
    #pragma unroll
    for (int mt = 0; mt < 2; mt++)
      #pragma unroll
      for (int nt = 0; nt < 2; nt++) {
        f32x4 a0 = acc[mt][nt];
        a0 = __builtin_amdgcn_mfma_f32_16x16x32_bf16(ah[mt], bh[nt], a0, 0, 0, 0);
        a0 = __builtin_amdgcn_mfma_f32_16x16x32_bf16(al[mt], bh[nt], a0, 0, 0, 0);
        a0 = __builtin_amdgcn_mfma_f32_16x16x32_bf16(ah[mt], bl[nt], a0, 0, 0, 0);
        acc[mt][nt] = a0;
      }
  }
  float tsum = 0.f;
  #pragma unroll
  for (int mt = 0; mt < 2; mt++)
    #pragma unroll
    for (int nt = 0; nt < 2; nt++)
      #pragma unroll
      for (int r = 0; r < 4; r++) {
        int row = brow + mt * 16 + (lane >> 4) * 4 + r;
        int col = wcol + nt * 16 + (lane & 15);
        int idx = row * 128 + col;
        float g = acc[mt][nt][r] * alpha;
        if (E1) g += beta * valU(E1, idx);
        if (row == col) g += delta;
        if (outBf) outBf[idx] = f2bf(g * aeff2);
        else storeDual(C, idx, g);
        tsum += g * g;
      }
  return tsum;
}

// ---------------- K1: Gram partials + class means ----------------
__global__ __launch_bounds__(256) void k_gt_partial(const float* __restrict__ X, float* __restrict__ ws) {
  __shared__ unsigned short xt[128 * 256]; // 64 KB
  int b = blockIdx.x, tid = threadIdx.x;
  const float* Xc = X + b * 256 * D;
  for (int idx = tid; idx < 256 * D; idx += 256) {
    int s = idx >> 7, d = idx & 127;
    unsigned byte = ((unsigned)(d * 512 + s * 2)) ^ (((unsigned)(d & 7)) << 4);
    *(unsigned short*)((char*)xt + byte) = f2bf(Xc[idx]);
  }
  {
    int d = tid & 127;
    for (int cc = (tid >> 7); cc < 4; cc += 2) {
      const float* p = Xc + cc * 64 * D + d;
      float s = 0.f;
      #pragma unroll
      for (int n = 0; n < 64; n++) s += p[n * D];
      ((unsigned short*)ws)[d * 256 + (b * 4 + cc)] = f2bf(s * (1.0f / 64.0f));
    }
  }
  __syncthreads();
  int w = tid >> 6, lane = tid & 63;
  int wr = (w >> 1) * 64, wc = (w & 1) * 64;
  f32x4 acc[4][4] = {};
  for (int ks = 0; ks < 8; ks++) {
    int kb = ks * 32 + (lane >> 4) * 8;
    short8 af[4];
    #pragma unroll
    for (int mt = 0; mt < 4; mt++) {
      int r = wr + mt * 16 + (lane & 15);
      unsigned byte = ((unsigned)(r * 512 + kb * 2)) ^ (((unsigned)(r & 7)) << 4);
      af[mt] = *(short8*)((char*)xt + byte);
    }
    #pragma unroll
    for (int nt = 0; nt < 4; nt++) {
      int c = wc + nt * 16 + (lane & 15);
      unsigned byte = ((unsigned)(c * 512 + kb * 2)) ^ (((unsigned)(c & 7)) << 4);
      short8 bfr = *(short8*)((char*)xt + byte);
      #pragma unroll
      for (int mt = 0; mt < 4; mt++)
        acc[mt][nt] = __builtin_amdgcn_mfma_f32_16x16x32_bf16(af[mt], bfr, acc[mt][nt], 0, 0, 0);
    }
  }
  float* outp = ws + fPART + b * 16384;
  #pragma unroll
  for (int mt = 0; mt < 4; mt++)
    #pragma unroll
    for (int nt = 0; nt < 4; nt++)
      #pragma unroll
      for (int r = 0; r < 4; r++) {
        int row = wr + mt * 16 + (lane >> 4) * 4 + r;
        int col = wc + nt * 16 + (lane & 15);
        outp[row * 128 + col] = acc[mt][nt][r];
      }
}

// ---------------- K2: reduce partials; blk0: mean; blk1: inv_s ----------------
__global__ void k_reduce(float* __restrict__ ws) {
  __shared__ float red2[4];
  int tid = threadIdx.x;
  int idx = blockIdx.x * 256 + tid;
  const float* part = ws + fPART;
  float s = 0.f;
  #pragma unroll 8
  for (int p = 0; p < 64; p++) s += part[p * 16384 + idx];
  ws[fSWRAW + idx] = s;
  if (blockIdx.x == 0 && tid < 128) {
    const unsigned short* McT = (const unsigned short*)ws;
    float m = 0.f;
    for (int k = 0; k < 256; k++) m += bf2f(McT[tid * 256 + k]);
    ws[fMEAN + tid] = m * (1.0f / 256.0f);
  }
  if (blockIdx.x == 1) {
    float v = 0.f;
    if (tid < 128) {
      float gdd = 0.f;
      for (int p = 0; p < 64; p++) gdd += part[p * 16384 + tid * 129];
      const unsigned short* McT = (const unsigned short*)ws;
      float nrm = 0.f;
      for (int k = 0; k < 256; k++) { float x = bf2f(McT[tid * 256 + k]); nrm += x * x; }
      v = gdd * (1.0f / COUNT) - nrm * (1.0f / 256.0f);
    }
    #pragma unroll
    for (int off = 32; off > 0; off >>= 1) v += __shfl_down(v, off);
    if ((tid & 63) == 0) red2[tid >> 6] = v;
    __syncthreads();
    if (tid == 0) {
      float inv_s = 128.0f / (red2[0] + red2[1] + red2[2] + red2[3]);
      ws[fSCAL + 1] = inv_s;
      ws[fSCAL + 7] = 0.984375f * inv_s;
    }
  }
}

// ---------------- K3: SB strip (K=256 MFMA) + P = S_wn - I strip ----------------
__global__ __launch_bounds__(256) void k_sbp(float* __restrict__ ws) {
  const unsigned short* Mc = (const unsigned short*)ws;
  const float* mv = ws + fMEAN;
  const float* swraw = ws + fSWRAW;
  float inv_s = ws[fSCAL + 1];
  unsigned short* SB = MS(ws, sSB);
  unsigned short* P = MS(ws, sP);
  int tid = threadIdx.x, b = blockIdx.x;
  int w = tid >> 6, lane = tid & 63;
  int brow = b * 32, wcol = w * 32;
  f32x4 acc[2][2] = {};
  for (int ks = 0; ks < 8; ks++) {
    int kb = ks * 32 + (lane >> 4) * 8;
    short8 af[2], bfv[2];
    #pragma unroll
    for (int mt = 0; mt < 2; mt++) {
      int r = brow + mt * 16 + (lane & 15);
      af[mt] = *(const short8*)(Mc + r * 256 + kb);
    }
    #pragma unroll
    for (int nt = 0; nt < 2; nt++) {
      int c = wcol + nt * 16 + (lane & 15);
      bfv[nt] = *(const short8*)(Mc + c * 256 + kb);
    }
    #pragma unroll
    for (int mt = 0; mt < 2; mt++)
      #pragma unroll
      for (int nt = 0; nt < 2; nt++)
        acc[mt][nt] = __builtin_amdgcn_mfma_f32_16x16x32_bf16(af[mt], bfv[nt], acc[mt][nt], 0, 0, 0);
  }
  #pragma unroll
  for (int mt = 0; mt < 2; mt++)
    #pragma unroll
    for (int nt = 0; nt < 2; nt++)
      #pragma unroll
      for (int r = 0; r < 4; r++) {
        int row = brow + mt * 16 + (lane >> 4) * 4 + r;
        int col = wcol + nt * 16 + (lane & 15);
        int idx = row * 128 + col;
        float g = acc[mt][nt][r] * (1.0f / 256.0f) - mv[row] * mv[col];
        storeDual(SB, idx, g);
        float s = (swraw[idx] * (1.0f / COUNT) - g - mv[row] * mv[col]) * inv_s;
        storeDual(P, idx, s - ((row == col) ? 1.0f : 0.0f));
      }
}

// ---------------- K4: strips P2 -> P3 -> P4 (+tr P^8) ----------------
__global__ __launch_bounds__(256) void k_pows(float* __restrict__ ws) {
  __shared__ unsigned short sA[8192];
  __shared__ unsigned short sB[8192];
  __shared__ float red[4];
  float* scal = ws + fSCAL;
  const unsigned short* P = MS(ws, sP);
  unsigned short* P2 = MS(ws, sP2);
  unsigned short* P3 = MS(ws, sP3);
  unsigned short* P4 = MS(ws, sP4);
  int tid = threadIdx.x, b = blockIdx.x;
  int w = tid >> 6, lane = tid & 63;
  int brow = b * 32, wcol = w * 32;
  // phase1: P2 strip = P[rows]*P
  {
    f32x4 acc[2][2] = {};
    #pragma unroll
    for (int ks = 0; ks < 4; ks++) {
      int kb = ks * 32 + (lane >> 4) * 8;
      short8 ah[2], al[2], bh[2], bl[2];
      #pragma unroll
      for (int mt = 0; mt < 2; mt++) {
        int r = brow + mt * 16 + (lane & 15);
        ah[mt] = *(const short8*)(P + r * 128 + kb);
        al[mt] = *(const short8*)(P + 16384 + r * 128 + kb);
      }
      #pragma unroll
      for (int nt = 0; nt < 2; nt++) {
        int c = wcol + nt * 16 + (lane & 15);
        bh[nt] = *(const short8*)(P + c * 128 + kb);
        bl[nt] = *(const short8*)(P + 16384 + c * 128 + kb);
      }
      #pragma unroll
      for (int mt = 0; mt < 2; mt++)
        #pragma unroll
        for (int nt = 0; nt < 2; nt++) {
          f32x4 a0 = acc[mt][nt];
          a0 = __builtin_amdgcn_mfma_f32_16x16x32_bf16(ah[mt], bh[nt], a0, 0, 0, 0);
          a0 = __builtin_amdgcn_mfma_f32_16x16x32_bf16(al[mt], bh[nt], a0, 0, 0, 0);
          a0 = __builtin_amdgcn_mfma_f32_16x16x32_bf16(ah[mt], bl[nt], a0, 0, 0, 0);
          acc[mt][nt] = a0;
        }
    }
    #pragma unroll
    for (int mt = 0; mt < 2; mt++)
      #pragma unroll
      for (int nt = 0; nt < 2; nt++)
        #pragma unroll
        for (int r = 0; r < 4; r++) {
          int rloc = mt * 16 + (lane >> 4) * 4 + r;
          int col = wcol + nt * 16 + (lane & 15);
          float g = acc[mt][nt][r];
          stPutDual(sA, rloc, col, g);
          storeDual(P2, (brow + rloc) * 128 + col, g);
        }
  }
  __syncthreads();
  // phase2: P3 strip = sA*P
  {
    f32x4 acc[2][2] = {};
    #pragma unroll
    for (int ks = 0; ks < 4; ks++) {
      int kb = ks * 32 + (lane >> 4) * 8;
      short8 ah[2], al[2], bh[2], bl[2];
      #pragma unroll
      for (int mt = 0; mt < 2; mt++) {
        int rloc = mt * 16 + (lane & 15);
        ah[mt] = st8(sA, rloc, kb);
        al[mt] = st8(sA + 4096, rloc, kb);
      }
      #pragma unroll
      for (int nt = 0; nt < 2; nt++) {
        int c = wcol + nt * 16 + (lane & 15);
        bh[nt] = *(const short8*)(P + c * 128 + kb);
        bl[nt] = *(const short8*)(P + 16384 + c * 128 + kb);
      }
      #pragma unroll
      for (int mt = 0; mt < 2; mt++)
        #pragma unroll
        for (int nt = 0; nt < 2; nt++) {
          f32x4 a0 = acc[mt][nt];
          a0 = __builtin_amdgcn_mfma_f32_16x16x32_bf16(ah[mt], bh[nt], a0, 0, 0, 0);
          a0 = __builtin_amdgcn_mfma_f32_16x16x32_bf16(al[mt], bh[nt], a0, 0, 0, 0);
          a0 = __builtin_amdgcn_mfma_f32_16x16x32_bf16(ah[mt], bl[nt], a0, 0, 0, 0);
          acc[mt][nt] = a0;
        }
    }
    #pragma unroll
    for (int mt = 0; mt < 2; mt++)
      #pragma unroll
      for (int nt = 0; nt < 2; nt++)
        #pragma unroll
        for (int r = 0; r < 4; r++) {
          int rloc = mt * 16 + (lane >> 4) * 4 + r;
          int col = wcol + nt * 16 + (lane & 15);
          float g = acc[mt][nt][r];
          stPutDual(sB, rloc, col, g);
          storeDual(P3, (brow + rloc) * 128 + col, g);
        }
  }
  __syncthreads();
  // phase3: P4 strip = sB*P (+||P4||^2 partial)
  float tsum = 0.f;
  {
    f32x4 acc[2][2] = {};
    #pragma unroll
    for (int ks = 0; ks < 4; ks++) {
      int kb = ks * 32 + (lane >> 4) * 8;
      short8 ah[2], al[2], bh[2], bl[2];
      #pragma unroll
      for (int mt = 0; mt < 2; mt++) {
        int rloc = mt * 16 + (lane & 15);
        ah[mt] = st8(sB, rloc, kb);
        al[mt] = st8(sB + 4096, rloc, kb);
      }
      #pragma unroll
      for (int nt = 0; nt < 2; nt++) {
        int c = wcol + nt * 16 + (lane & 15);
        bh[nt] = *(const short8*)(P + c * 128 + kb);
        bl[nt] = *(const short8*)(P + 16384 + c * 128 + kb);
      }
      #pragma unroll
      for (int mt = 0; mt < 2; mt++)
        #pragma unroll
        for (int nt = 0; nt < 2; nt++) {
          f32x4 a0 = acc[mt][nt];
          a0 = __builtin_amdgcn_mfma_f32_16x16x32_bf16(ah[mt], bh[nt], a0, 0, 0, 0);
          a0 = __builtin_amdgcn_mfma_f32_16x16x32_bf16(al[mt], bh[nt], a0, 0, 0, 0);
          a0 = __builtin_amdgcn_mfma_f32_16x16x32_bf16(ah[mt], bl[nt], a0, 0, 0, 0);
          acc[mt][nt] = a0;
        }
    }
    #pragma unroll
    for (int mt = 0; mt < 2; mt++)
      #pragma unroll
      for (int nt = 0; nt < 2; nt++)
        #pragma unroll
        for (int r = 0; r < 4; r++) {
          int rloc = mt * 16 + (lane >> 4) * 4 + r;
          int col = wcol + nt * 16 + (lane & 15);
          float g = acc[mt][nt][r];
          storeDual(P4, (brow + rloc) * 128 + col, g);
          tsum += g * g;
        }
  }
  #pragma unroll
  for (int off = 32; off > 0; off >>= 1) tsum += __shfl_down(tsum, off);
  if (lane == 0) red[w] = tsum;
  __syncthreads();
  if (tid == 0) scal[60 + b] = red[0] + red[1] + red[2] + red[3];
}

// ---------------- K5: P5,P6 in-reg + Z = sum beta_k P^k ----------------
__global__ __launch_bounds__(256) void k_z(float* __restrict__ ws) {
  __shared__ float cj[7];
  __shared__ float bt[7];
  float* scal = ws + fSCAL;
  const unsigned short *P = MS(ws, sP), *P2 = MS(ws, sP2),
    *P3 = MS(ws, sP3), *P4 = MS(ws, sP4);
  unsigned short* Z = MS(ws, sZ);
  int tid = threadIdx.x, b = blockIdx.x;
  float trP8 = scal[60] + scal[61] + scal[62] + scal[63];
  float a = 1.05f * sqrtf(sqrtf(sqrtf(fmaxf(trP8, 1e-30f))));
  a = fminf(a, 0.95f);
  if (tid < 7) {
    const float PI = 3.14159265358979f;
    float s = 0.f;
    for (int i = 0; i < 64; i++) {
      float th = (i + 0.5f) * (PI / 64.0f);
      float x = cosf(th);
      s += (1.0f / sqrtf(1.0f + a * x)) * cosf((float)tid * th);
    }
    cj[tid] = s * (2.0f / 64.0f);
  }
  __syncthreads();
  if (tid == 0) {
    float c0h = 0.5f * cj[0];
    float m0 = c0h - cj[2] + cj[4] - cj[6];
    float m1 = cj[1] - 3.0f * cj[3] + 5.0f * cj[5];
    float m2 = 2.0f * cj[2] - 8.0f * cj[4] + 18.0f * cj[6];
    float m3 = 4.0f * cj[3] - 20.0f * cj[5];
    float m4 = 8.0f * cj[4] - 48.0f * cj[6];
    float m5 = 16.0f * cj[5];
    float m6 = 32.0f * cj[6];
    float ia = 1.0f / a, p = 1.f;
    bt[0] = m0;
    p *= ia; bt[1] = m1 * p;
    p *= ia; bt[2] = m2 * p;
    p *= ia; bt[3] = m3 * p;
    p *= ia; bt[4] = m4 * p;
    p *= ia; bt[5] = m5 * p;
    p *= ia; bt[6] = m6 * p;
  }
  __syncthreads();
  int w = tid >> 6, lane = tid & 63;
  int brow = b * 32, wcol = w * 32;
  f32x4 a5[2][2] = {}, a6[2][2] = {};
  #pragma unroll
  for (int ks = 0; ks < 4; ks++) {
    int kb = ks * 32 + (lane >> 4) * 8;
    short8 ah[2], al[2], b5h[2], b5l[2], b6h[2], b6l[2];
    #pragma unroll
    for (int mt = 0; mt < 2; mt++) {
      int r = brow + mt * 16 + (lane & 15);
      ah[mt] = *(const short8*)(P4 + r * 128 + kb);
      al[mt] = *(const short8*)(P4 + 16384 + r * 128 + kb);
    }
    #pragma unroll
    for (int nt = 0; nt < 2; nt++) {
      int c = wcol + nt * 16 + (lane & 15);
      b5h[nt] = *(const short8*)(P + c * 128 + kb);
      b5l[nt] = *(const short8*)(P + 16384 + c * 128 + kb);
      b6h[nt] = *(const short8*)(P2 + c * 128 + kb);
      b6l[nt] = *(const short8*)(P2 + 16384 + c * 128 + kb);
    }
    #pragma unroll
    for (int mt = 0; mt < 2; mt++)
      #pragma unroll
      for (int nt = 0; nt < 2; nt++) {
        f32x4 x5 = a5[mt][nt];
        x5 = __builtin_amdgcn_mfma_f32_16x16x32_bf16(ah[mt], b5h[nt], x5, 0, 0, 0);
        x5 = __builtin_amdgcn_mfma_f32_16x16x32_bf16(al[mt], b5h[nt], x5, 0, 0, 0);
        x5 = __builtin_amdgcn_mfma_f32_16x16x32_bf16(ah[mt], b5l[nt], x5, 0, 0, 0);
        a5[mt][nt] = x5;
        f32x4 x6 = a6[mt][nt];
        x6 = __builtin_amdgcn_mfma_f32_16x16x32_bf16(ah[mt], b6h[nt], x6, 0, 0, 0);
        x6 = __builtin_amdgcn_mfma_f32_16x16x32_bf16(al[mt], b6h[nt], x6, 0, 0, 0);
        x6 = __builtin_amdgcn_mfma_f32_16x16x32_bf16(ah[mt], b6l[nt], x6, 0, 0, 0);
        a6[mt][nt] = x6;
      }
  }
  #pragma unroll
  for (int mt = 0; mt < 2; mt++)
    #pragma unroll
    for (int nt = 0; nt < 2; nt++)
      #pragma unroll
      for (int r = 0; r < 4; r++) {
        int row = brow + mt * 16 + (lane >> 4) * 4 + r;
        int col = wcol + nt * 16 + (lane & 15);
        int idx = row * 128 + col;
        float dg = (row == col) ? 1.0f : 0.0f;
        float z = bt[0] * dg + bt[1] * valU(P, idx) + bt[2] * valU(P2, idx) +
                  bt[3] * valU(P3, idx) + bt[4] * valU(P4, idx) +
                  bt[5] * a5[mt][nt][r] + bt[6] * a6[mt][nt][r];
        storeDual(Z, idx, z);
      }
}

// ---------------- K6: M1 strip (LDS) -> Mm strip ----------------
__global__ __launch_bounds__(256) void k_m(float* __restrict__ ws) {
  __shared__ unsigned short sA[8192];
  const unsigned short* Z = MS(ws, sZ);
  const unsigned short* SB = MS(ws, sSB);
  unsigned short* Mm = MS(ws, sMm);
  int tid = threadIdx.x, b = blockIdx.x;
  int w = tid >> 6, lane = tid & 63;
  int brow = b * 32, wcol = w * 32;
  {
    f32x4 acc[2][2] = {};
    #pragma unroll
    for (int ks = 0; ks < 4; ks++) {
      int kb = ks * 32 + (lane >> 4) * 8;
      short8 ah[2], al[2], bh[2], bl[2];
      #pragma unroll
      for (int mt = 0; mt < 2; mt++) {
        int r = brow + mt * 16 + (lane & 15);
        ah[mt] = *(const short8*)(Z + r * 128 + kb);
        al[mt] = *(const short8*)(Z + 16384 + r * 128 + kb);
      }
      #pragma unroll
      for (int nt = 0; nt < 2; nt++) {
        int c = wcol + nt * 16 + (lane & 15);
        bh[nt] = *(const short8*)(SB + c * 128 + kb);
        bl[nt] = *(const short8*)(SB + 16384 + c * 128 + kb);
      }
      #pragma unroll
      for (int mt = 0; mt < 2; mt++)
        #pragma unroll
        for (int nt = 0; nt < 2; nt++) {
          f32x4 a0 = acc[mt][nt];
          a0 = __builtin_amdgcn_mfma_f32_16x16x32_bf16(ah[mt], bh[nt], a0, 0, 0, 0);
          a0 = __builtin_amdgcn_mfma_f32_16x16x32_bf16(al[mt], bh[nt], a0, 0, 0, 0);
          a0 = __builtin_amdgcn_mfma_f32_16x16x32_bf16(ah[mt], bl[nt], a0, 0, 0, 0);
          acc[mt][nt] = a0;
        }
    }
    #pragma unroll
    for (int mt = 0; mt < 2; mt++)
      #pragma unroll
      for (int nt = 0; nt < 2; nt++)
        #pragma unroll
        for (int r = 0; r < 4; r++) {
          int rloc = mt * 16 + (lane >> 4) * 4 + r;
          int col = wcol + nt * 16 + (lane & 15);
          stPutDual(sA, rloc, col, acc[mt][nt][r]);
        }
  }
  __syncthreads();
  {
    f32x4 acc[2][2] = {};
    #pragma unroll
    for (int ks = 0; ks < 4; ks++) {
      int kb = ks * 32 + (lane >> 4) * 8;
      short8 ah[2], al[2], bh[2], bl[2];
      #pragma unroll
      for (int mt = 0; mt < 2; mt++) {
        int rloc = mt * 16 + (lane & 15);
        ah[mt] = st8(sA, rloc, kb);
        al[mt] = st8(sA + 4096, rloc, kb);
      }
      #pragma unroll
      for (int nt = 0; nt < 2; nt++) {
        int c = wcol + nt * 16 + (lane & 15);
        bh[nt] = *(const short8*)(Z + c * 128 + kb);
        bl[nt] = *(const short8*)(Z + 16384 + c * 128 + kb);
      }
      #pragma unroll
      for (int mt = 0; mt < 2; mt++)
        #pragma unroll
        for (int nt = 0; nt < 2; nt++) {
          f32x4 a0 = acc[mt][nt];
          a0 = __builtin_amdgcn_mfma_f32_16x16x32_bf16(ah[mt], bh[nt], a0, 0, 0, 0);
          a0 = __builtin_amdgcn_mfma_f32_16x16x32_bf16(al[mt], bh[nt], a0, 0, 0, 0);
          a0 = __builtin_amdgcn_mfma_f32_16x16x32_bf16(ah[mt], bl[nt], a0, 0, 0, 0);
          acc[mt][nt] = a0;
        }
    }
    #pragma unroll
    for (int mt = 0; mt < 2; mt++)
      #pragma unroll
      for (int nt = 0; nt < 2; nt++)
        #pragma unroll
        for (int r = 0; r < 4; r++) {
          int rloc = mt * 16 + (lane >> 4) * 4 + r;
          int col = wcol + nt * 16 + (lane & 15);
          storeDual(Mm, (brow + rloc) * 128 + col, acc[mt][nt][r]);
        }
  }
}

// ---------------- K7: C2 strip (+tr M^4 partial) ----------------
__global__ __launch_bounds__(256) void k_c2(float* __restrict__ ws) {
  __shared__ float red[4];
  float* scal = ws + fSCAL;
  const unsigned short* Mm = MS(ws, sMm);
  int tid = threadIdx.x, b = blockIdx.x;
  int w = tid >> 6, lane = tid & 63;
  float tsum = mm_core(Mm, Mm, MS(ws, sC2), nullptr, 1.0f, 0.0f, 0.0f, b * 32, nullptr, 1.0f);
  #pragma unroll
  for (int off = 32; off > 0; off >>= 1) tsum += __shfl_down(tsum, off);
  if (lane == 0) red[w] = tsum;
  __syncthreads();
  if (tid == 0) scal[68 + b] = red[0] + red[1] + red[2] + red[3];
}

// interval from tr M^4 = ||C2||_F^2
__device__ inline void interval_cs(const float* scal, float* c0o, float* iho) {
  float trM4 = scal[68] + scal[69] + scal[70] + scal[71];
  float Lam = 1.03f * sqrtf(sqrtf(fmaxf(trM4, 1e-37f)));
  float lo = -0.02f * Lam, hi = Lam;
  *c0o = 0.5f * (hi + lo);
  *iho = 1.0f / (0.5f * (hi - lo));
}

// ---------------- K8: XH, T2 elementwise ----------------
__global__ __launch_bounds__(256) void k_xh_t2(float* __restrict__ ws) {
  __shared__ float cs[2];
  float* scal = ws + fSCAL;
  if (threadIdx.x == 0) {
    float c0, ih;
    interval_cs(scal, &c0, &ih);
    cs[0] = c0; cs[1] = ih;
  }
  __syncthreads();
  float c0 = cs[0], ih = cs[1];
  float a2 = 2.0f * ih * ih, b2 = -4.0f * c0 * ih * ih, g2 = 2.0f * c0 * c0 * ih * ih - 1.0f;
  const unsigned short* Mm = MS(ws, sMm);
  const unsigned short* C2 = MS(ws, sC2);
  unsigned short* XH = MS(ws, sXH);
  unsigned short* T2 = MS(ws, sT2);
  int gid = blockIdx.x * 256 + threadIdx.x;
  #pragma unroll
  for (int t = 0; t < 4; t++) {
    int idx = gid * 4 + t;
    int row = idx >> 7, col = idx & 127;
    float m = valU(Mm, idx), c2v = valU(C2, idx);
    float dg = (row == col) ? 1.0f : 0.0f;
    storeDual(XH, idx, ih * m - ih * c0 * dg);
    storeDual(T2, idx, a2 * c2v + b2 * m + g2 * dg);
  }
}

// ---------------- K9: T3 = 2 XH T2 - XH (blk 0-3) | T4 = 2 T2^2 - I (blk 4-7) ----------------
__global__ __launch_bounds__(256) void k_t34(float* __restrict__ ws) {
  const unsigned short* XH = MS(ws, sXH);
  const unsigned short* T2 = MS(ws, sT2);
  if (blockIdx.x < 4) {
    mm_core(XH, T2, MS(ws, sT3), XH, 2.0f, -1.0f, 0.0f, blockIdx.x * 32, nullptr, 1.0f);
  } else {
    mm_core(T2, T2, MS(ws, sT4), nullptr, 2.0f, 0.0f, -1.0f, (blockIdx.x - 4) * 32, nullptr, 1.0f);
  }
}

// ---------------- K10: blk 0-3: T5 = 2 T3 T2 - XH; blk 4-19: G0..G4 ----------------
__global__ __launch_bounds__(256) void k_t5g(float* __restrict__ ws) {
  __shared__ float cs[8];
  __shared__ float sat[25];
  __shared__ float sc[25];
  float* scal = ws + fSCAL;
  int tid = threadIdx.x;
  if (blockIdx.x < 4) {
    mm_core(MS(ws, sT3), MS(ws, sT2), MS(ws, sT5), MS(ws, sXH),
            2.0f, -1.0f, 0.0f, blockIdx.x * 32, nullptr, 1.0f);
    return;
  }
  if (tid == 0) {
    float c0, ih;
    interval_cs(scal, &c0, &ih);
    float inv_s = scal[1];
    float t0 = (1.0f / 63.0f) / inv_s;
    float x0 = fminf(fmaxf((t0 - c0) * ih, -1.0f), 1.0f);
    cs[0] = acosf(x0); cs[1] = x0;
    cs[2] = 0.984375f * inv_s / ih;
  }
  __syncthreads();
  if (tid <= 24) {
    float th = cs[0], x0 = cs[1], SCc = cs[2];
    const float PI = 3.14159265358979f;
    float v;
    if (tid == 0) v = 0.5f * SCc * (2.0f / PI) * (sinf(th) - x0 * th);
    else if (tid == 1) v = SCc * (2.0f / PI) * (0.5f * th + 0.25f * sinf(2.0f * th) - x0 * sinf(th));
    else {
      float fj = (float)tid;
      v = SCc * (2.0f / PI) *
          (0.5f * (sinf((fj + 1.0f) * th) / (fj + 1.0f) + sinf((fj - 1.0f) * th) / (fj - 1.0f))
           - x0 * sinf(fj * th) / fj);
    }
    sat[tid] = v;
    sc[tid] = 0.f;
  }
  __syncthreads();
  if (tid == 0) {
    for (int j = 24; j >= 5; --j) {
      int k = j / 5, r = j - 5 * k;
      float aj = sat[j];
      if (r == 0) sc[k * 5] += aj;
      else { sc[k * 5 + r] += 2.0f * aj; sat[5 * k - r] -= aj; }
    }
    for (int r = 0; r < 5; r++) sc[r] += sat[r];
  }
  __syncthreads();
  const unsigned short* XH = MS(ws, sXH);
  const unsigned short* T2 = MS(ws, sT2);
  const unsigned short* T3 = MS(ws, sT3);
  const unsigned short* T4 = MS(ws, sT4);
  int bg = blockIdx.x - 4;
  int base = bg * 1024 + tid * 4;
  #pragma unroll
  for (int t = 0; t < 4; t++) {
    int idx = base + t;
    int row = idx >> 7, col = idx & 127;
    float dg = (row == col) ? 1.0f : 0.0f;
    float x1 = valU(XH, idx), x2 = valU(T2, idx), x3 = valU(T3, idx), x4 = valU(T4, idx);
    #pragma unroll
    for (int k = 0; k < 5; k++) {
      float g = sc[k * 5 + 0] * dg + sc[k * 5 + 1] * x1 + sc[k * 5 + 2] * x2 +
                sc[k * 5 + 3] * x3 + sc[k * 5 + 4] * x4;
      storeDual(MS(ws, sG0 + k), idx, g);
    }
  }
}

// ---------------- K11: strips T10 -> T15 -> T20 (T20 = 2 T15 T5 - T10) ----------------
__global__ __launch_bounds__(256) void k_thi(float* __restrict__ ws) {
  __shared__ unsigned short sA[8192]; // T10 strip
  __shared__ unsigned short sB[8192]; // T15 strip
  const unsigned short* T5 = MS(ws, sT5);
  unsigned short* T10 = MS(ws, sT10);
  unsigned short* T15 = MS(ws, sT15);
  unsigned short* T20 = MS(ws, sT20);
  int tid = threadIdx.x, b = blockIdx.x;
  int w = tid >> 6, lane = tid & 63;
  int brow = b * 32, wcol = w * 32;
  // phase1: T10 strip = 2*T5[rows]*T5 - I
  {
    f32x4 acc[2][2] = {};
    #pragma unroll
    for (int ks = 0; ks < 4; ks++) {
      int kb = ks * 32 + (lane >> 4) * 8;
      short8 ah[2], al[2], bh[2], bl[2];
      #pragma unroll
      for (int mt = 0; mt < 2; mt++) {
        int r = brow + mt * 16 + (lane & 15);
        ah[mt] = *(const short8*)(T5 + r * 128 + kb);
        al[mt] = *(const short8*)(T5 + 16384 + r * 128 + kb);
      }
      #pragma unroll
      for (int nt = 0; nt < 2; nt++) {
        int c = wcol + nt * 16 + (lane & 15);
        bh[nt] = *(const short8*)(T5 + c * 128 + kb);
        bl[nt] = *(const short8*)(T5 + 16384 + c * 128 + kb);
      }
      #pragma unroll
      for (int mt = 0; mt < 2; mt++)
        #pragma unroll
        for (int nt = 0; nt < 2; nt++) {
          f32x4 a0 = acc[mt][nt];
          a0 = __builtin_amdgcn_mfma_f32_16x16x32_bf16(ah[mt], bh[nt], a0, 0, 0, 0);
          a0 = __builtin_amdgcn_mfma_f32_16x16x32_bf16(al[mt], bh[nt], a0, 0, 0, 0);
          a0 = __builtin_amdgcn_mfma_f32_16x16x32_bf16(ah[mt], bl[nt], a0, 0, 0, 0);
          acc[mt][nt] = a0;
        }
    }
    #pragma unroll
    for (int mt = 0; mt < 2; mt++)
      #pragma unroll
      for (int nt = 0; nt < 2; nt++)
        #pragma unroll
        for (int r = 0; r < 4; r++) {
          int rloc = mt * 16 + (lane >> 4) * 4 + r;
          int col = wcol + nt * 16 + (lane & 15);
          int row = brow + rloc;
          float g = 2.0f * acc[mt][nt][r] - ((row == col) ? 1.0f : 0.0f);
          stPutDual(sA, rloc, col, g);
          storeDual(T10, row * 128 + col, g);
        }
  }
  __syncthreads();
  // phase2: T15 strip = 2*sA*T5 - T5[rows]
  {
    f32x4 acc[2][2] = {};
    #pragma unroll
    for (int ks = 0; ks < 4; ks++) {
      int kb = ks * 32 + (lane >> 4) * 8;
      short8 ah[2], al[2], bh[2], bl[2];
      #pragma unroll
      for (int mt = 0; mt < 2; mt++) {
        int rloc = mt * 16 + (lane & 15);
        ah[mt] = st8(sA, rloc, kb);
        al[mt] = st8(sA + 4096, rloc, kb);
      }
      #pragma unroll
      for (int nt = 0; nt < 2; nt++) {
        int c = wcol + nt * 16 + (lane & 15);
        bh[nt] = *(const short8*)(T5 + c * 128 + kb);
        bl[nt] = *(const short8*)(T5 + 16384 + c * 128 + kb);
      }
      #pragma unroll
      for (int mt = 0; mt < 2; mt++)
        #pragma unroll
        for (int nt = 0; nt < 2; nt++) {
          f32x4 a0 = acc[mt][nt];
          a0 = __builtin_amdgcn_mfma_f32_16x16x32_bf16(ah[mt], bh[nt], a0, 0, 0, 0);
          a0 = __builtin_amdgcn_mfma_f32_16x16x32_bf16(al[mt], bh[nt], a0, 0, 0, 0);
          a0 = __builtin_amdgcn_mfma_f32_16x16x32_bf16(ah[mt], bl[nt], a0, 0, 0, 0);
          acc[mt][nt] = a0;
        }
    }
    #pragma unroll
    for (int mt = 0; mt < 2; mt++)
      #pragma unroll
      for (int nt = 0; nt < 2; nt++)
        #pragma unroll
        for (int r = 0; r < 4; r++) {
          int rloc = mt * 16 + (lane >> 4) * 4 + r;
          int col = wcol + nt * 16 + (lane & 15);
          int idx = (brow + rloc) * 128 + col;
          float g = 2.0f * acc[mt][nt][r] - valU(T5, idx);
          stPutDual(sB, rloc, col, g);
          storeDual(T15, idx, g);
        }
  }
  __syncthreads();
  // phase3: T20 strip = 2*sB*T5 - sA(T10)
  {
    f32x4 acc[2][2] = {};
    #pragma unroll
    for (int ks = 0; ks < 4; ks++) {
      int kb = ks * 32 + (lane >> 4) * 8;
      short8 ah[2], al[2], bh[2], bl[2];
      #pragma unroll
      for (int mt = 0; mt < 2; mt++) {
        int rloc = mt * 16 + (lane & 15);
        ah[mt] = st8(sB, rloc, kb);
        al[mt] = st8(sB + 4096, rloc, kb);
      }
      #pragma unroll
      for (int nt = 0; nt < 2; nt++) {
        int c = wcol + nt * 16 + (lane & 15);
        bh[nt] = *(const short8*)(T5 + c * 128 + kb);
        bl[nt] = *(const short8*)(T5 + 16384 + c * 128 + kb);
      }
      #pragma unroll
      for (int mt = 0; mt < 2; mt++)
        #pragma unroll
        for (int nt = 0; nt < 2; nt++) {
          f32x4 a0 = acc[mt][nt];
          a0 = __builtin_amdgcn_mfma_f32_16x16x32_bf16(ah[mt], bh[nt], a0, 0, 0, 0);
          a0 = __builtin_amdgcn_mfma_f32_16x16x32_bf16(al[mt], bh[nt], a0, 0, 0, 0);
          a0 = __builtin_amdgcn_mfma_f32_16x16x32_bf16(ah[mt], bl[nt], a0, 0, 0, 0);
          acc[mt][nt] = a0;
        }
    }
    #pragma unroll
    for (int mt = 0; mt < 2; mt++)
      #pragma unroll
      for (int nt = 0; nt < 2; nt++)
        #pragma unroll
        for (int r = 0; r < 4; r++) {
          int rloc = mt * 16 + (lane >> 4) * 4 + r;
          int col = wcol + nt * 16 + (lane & 15);
          float g = 2.0f * acc[mt][nt][r] - stValU(sA, rloc, col);
          storeDual(T20, (brow + rloc) * 128 + col, g);
        }
  }
}

// ---------------- K12: F = G0 + T5 G1 + T10 G2 + T15 G3 + T20 G4 (+trF2) ----------------
__global__ __launch_bounds__(256) void k_bigF(float* __restrict__ ws) {
  __shared__ float red[4];
  float* scal = ws + fSCAL;
  const unsigned short* As[4] = { MS(ws, sT5), MS(ws, sT10), MS(ws, sT15), MS(ws, sT20) };
  const unsigned short* Bs[4] = { MS(ws, sG0 + 1), MS(ws, sG0 + 2), MS(ws, sG0 + 3), MS(ws, sG0 + 4) };
  const unsigned short* G0 = MS(ws, sG0);
  unsigned short* Fm = MS(ws, sF);
  int tid = threadIdx.x, b = blockIdx.x;
  int w = tid >> 6, lane = tid & 63;
  int brow = b * 32, wcol = w * 32;
  f32x4 acc[2][2] = {};
  for (int p = 0; p < 4; p++) {
    const unsigned short* A = As[p];
    const unsigned short* B = Bs[p];
    #pragma unroll
    for (int ks = 0; ks < 4; ks++) {
      int kb = ks * 32 + (lane >> 4) * 8;
      short8 ah[2], al[2], bh[2], bl[2];
      #pragma unroll
      for (int mt = 0; mt < 2; mt++) {
        int r = brow + mt * 16 + (lane & 15);
        ah[mt] = *(const short8*)(A + r * 128 + kb);
        al[mt] = *(const short8*)(A + 16384 + r * 128 + kb);
      }
      #pragma unroll
      for (int nt = 0; nt < 2; nt++) {
        int c = wcol + nt * 16 + (lane & 15);
        bh[nt] = *(const short8*)(B + c * 128 + kb);
        bl[nt] = *(const short8*)(B + 16384 + c * 128 + kb);
      }
      #pragma unroll
      for (int mt = 0; mt < 2; mt++)
        #pragma unroll
        for (int nt = 0; nt < 2; nt++) {
          f32x4 a0 = acc[mt][nt];
          a0 = __builtin_amdgcn_mfma_f32_16x16x32_bf16(ah[mt], bh[nt], a0, 0, 0, 0);
          a0 = __builtin_amdgcn_mfma_f32_16x16x32_bf16(al[mt], bh[nt], a0, 0, 0, 0);
          a0 = __builtin_amdgcn_mfma_f32_16x16x32_bf16(ah[mt], bl[nt], a0, 0, 0, 0);
          acc[mt][nt] = a0;
        }
    }
  }
  float tsum = 0.f;
  #pragma unroll
  for (int mt = 0; mt < 2; mt++)
    #pragma unroll
    for (int nt = 0; nt < 2; nt++)
      #pragma unroll
      for (int r = 0; r < 4; r++) {
        int row = brow + mt * 16 + (lane >> 4) * 4 + r;
        int col = wcol + nt * 16 + (lane & 15);
        int idx = row * 128 + col;
        float g = acc[mt][nt][r] + valU(G0, idx);
        storeDual(Fm, idx, g);
        tsum += g * g;
      }
  #pragma unroll
  for (int off = 32; off > 0; off >>= 1) tsum += __shfl_down(tsum, off);
  if (lane == 0) red[w] = tsum;
  __syncthreads();
  if (tid == 0) scal[72 + b] = red[0] + red[1] + red[2] + red[3];
}

// ---------------- K13: A1 strip (LDS) -> Bbf strip ----------------
__global__ __launch_bounds__(256) void k_b(float* __restrict__ ws) {
  __shared__ unsigned short sA[8192];
  const unsigned short* Z = MS(ws, sZ);
  const unsigned short* Fm = MS(ws, sF);
  unsigned short* Bbf = (unsigned short*)(ws + fBBF);
  float aeff = ws[fSCAL + 7];
  int tid = threadIdx.x, b = blockIdx.x;
  int w = tid >> 6, lane = tid & 63;
  int brow = b * 32, wcol = w * 32;
  {
    f32x4 acc[2][2] = {};
    #pragma unroll
    for (int ks = 0; ks < 4; ks++) {
      int kb = ks * 32 + (lane >> 4) * 8;
      short8 ah[2], al[2], bh[2], bl[2];
      #pragma unroll
      for (int mt = 0; mt < 2; mt++) {
        int r = brow + mt * 16 + (lane & 15);
        ah[mt] = *(const short8*)(Z + r * 128 + kb);
        al[mt] = *(const short8*)(Z + 16384 + r * 128 + kb);
      }
      #pragma unroll
      for (int nt = 0; nt < 2; nt++) {
        int c = wcol + nt * 16 + (lane & 15);
        bh[nt] = *(const short8*)(Fm + c * 128 + kb);
        bl[nt] = *(const short8*)(Fm + 16384 + c * 128 + kb);
      }
      #pragma unroll
      for (int mt = 0; mt < 2; mt++)
        #pragma unroll
        for (int nt = 0; nt < 2; nt++) {
          f32x4 a0 = acc[mt][nt];
          a0 = __builtin_amdgcn_mfma_f32_16x16x32_bf16(ah[mt], bh[nt], a0, 0, 0, 0);
          a0 = __builtin_amdgcn_mfma_f32_16x16x32_bf16(al[mt], bh[nt], a0, 0, 0, 0);
          a0 = __builtin_amdgcn_mfma_f32_16x16x32_bf16(ah[mt], bl[nt], a0, 0, 0, 0);
          acc[mt][nt] = a0;
        }
    }
    #pragma unroll
    for (int mt = 0; mt < 2; mt++)
      #pragma unroll
      for (int nt = 0; nt < 2; nt++)
        #pragma unroll
        for (int r = 0; r < 4; r++) {
          int rloc = mt * 16 + (lane >> 4) * 4 + r;
          int col = wcol + nt * 16 + (lane & 15);
          stPutDual(sA, rloc, col, acc[mt][nt][r]);
        }
  }
  __syncthreads();
  {
    f32x4 acc[2][2] = {};
    #pragma unroll
    for (int ks = 0; ks < 4; ks++) {
      int kb = ks * 32 + (lane >> 4) * 8;
      short8 ah[2], al[2], bh[2], bl[2];
      #pragma unroll
      for (int mt = 0; mt < 2; mt++) {
        int rloc = mt * 16 + (lane & 15);
        ah[mt] = st8(sA, rloc, kb);
        al[mt] = st8(sA + 4096, rloc, kb);
      }
      #pragma unroll
      for (int nt = 0; nt < 2; nt++) {
        int c = wcol + nt * 16 + (lane & 15);
        bh[nt] = *(const short8*)(Z + c * 128 + kb);
        bl[nt] = *(const short8*)(Z + 16384 + c * 128 + kb);
      }
      #pragma unroll
      for (int mt = 0; mt < 2; mt++)
        #pragma unroll
        for (int nt = 0; nt < 2; nt++) {
          f32x4 a0 = acc[mt][nt];
          a0 = __builtin_amdgcn_mfma_f32_16x16x32_bf16(ah[mt], bh[nt], a0, 0, 0, 0);
          a0 = __builtin_amdgcn_mfma_f32_16x16x32_bf16(al[mt], bh[nt], a0, 0, 0, 0);
          a0 = __builtin_amdgcn_mfma_f32_16x16x32_bf16(ah[mt], bl[nt], a0, 0, 0, 0);
          acc[mt][nt] = a0;
        }
    }
    #pragma unroll
    for (int mt = 0; mt < 2; mt++)
      #pragma unroll
      for (int nt = 0; nt < 2; nt++)
        #pragma unroll
        for (int r = 0; r < 4; r++) {
          int rloc = mt * 16 + (lane >> 4) * 4 + r;
          int col = wcol + nt * 16 + (lane & 15);
          Bbf[(brow + rloc) * 128 + col] = f2bf(acc[mt][nt][r] * aeff);
        }
  }
}

// ---------------- K14: V = test - mean; U = V*B; q; blk0: log_div ----------------
__global__ __launch_bounds__(256) void k_latent(const float* __restrict__ test, float* __restrict__ ws) {
  __shared__ unsigned short vh[16384];
  __shared__ float qs[128];
  int blk = blockIdx.x, tid = threadIdx.x;
  if (blk == 0 && tid == 0) {
    float* scal = ws + fSCAL;
    float trF2 = fmaxf(scal[72] + scal[73] + scal[74] + scal[75], 1e-30f);
    scal[0] = 0.5f * (128.0f * 1.8378770664093453f + 0.5f * logf(trF2));
  }
  const float* tb = test + blk * 128 * D;
  unsigned short* Vbf = (unsigned short*)(ws + fV);
  if (tid < 128) qs[tid] = 0.f;
  for (int idx = tid; idx < 16384; idx += 256) {
    int r = idx >> 7, c = idx & 127;
    float v = tb[idx] - ws[fMEAN + c];
    unsigned short h = f2bf(v);
    unsigned byte = ((unsigned)(r * 256 + c * 2)) ^ (((unsigned)(r & 7)) << 4);
    *(unsigned short*)((char*)vh + byte) = h;
    Vbf[blk * 16384 + idx] = h;
  }
  __syncthreads();
  int w = tid >> 6, lane = tid & 63;
  int wr = (w >> 1) * 64, wc = (w & 1) * 64;
  const unsigned short* Bbf = (const unsigned short*)(ws + fBBF);
  f32x4 acc[4][4] = {};
  for (int ks = 0; ks < 4; ks++) {
    int kb = ks * 32 + (lane >> 4) * 8;
    short8 af[4], bfv[4];
    #pragma unroll
    for (int mt = 0; mt < 4; mt++) {
      int r = wr + mt * 16 + (lane & 15);
      unsigned byte = ((unsigned)(r * 256 + kb * 2)) ^ (((unsigned)(r & 7)) << 4);
      af[mt] = *(short8*)((char*)vh + byte);
    }
    #pragma unroll
    for (int nt = 0; nt < 4; nt++) {
      int c = wc + nt * 16 + (lane & 15);
      bfv[nt] = *(const short8*)(Bbf + c * 128 + kb);
    }
    #pragma unroll
    for (int mt = 0; mt < 4; mt++)
      #pragma unroll
      for (int nt = 0; nt < 4; nt++)
        acc[mt][nt] = __builtin_amdgcn_mfma_f32_16x16x32_bf16(af[mt], bfv[nt], acc[mt][nt], 0, 0, 0);
  }
  unsigned short* Ubf = (unsigned short*)(ws + fU);
  #pragma unroll
  for (int mt = 0; mt < 4; mt++)
    #pragma unroll
    for (int nt = 0; nt < 4; nt++)
      #pragma unroll
      for (int r = 0; r < 4; r++) {
        int row = wr + mt * 16 + (lane >> 4) * 4 + r;
        int col = wc + nt * 16 + (lane & 15);
        Ubf[(blk * 128 + row) * 128 + col] = f2bf(acc[mt][nt][r]);
      }
  #pragma unroll
  for (int mt = 0; mt < 4; mt++)
    #pragma unroll
    for (int r = 0; r < 4; r++) {
      int row = wr + mt * 16 + (lane >> 4) * 4 + r;
      float p = 0.f;
      #pragma unroll
      for (int nt = 0; nt < 4; nt++) {
        int col = wc + nt * 16 + (lane & 15);
        unsigned byte = ((unsigned)(row * 256 + col * 2)) ^ (((unsigned)(row & 7)) << 4);
        p += bf2f(f2bf(acc[mt][nt][r])) * bf2f(*(unsigned short*)((char*)vh + byte));
      }
      p += __shfl_xor(p, 1, 16);
      p += __shfl_xor(p, 2, 16);
      p += __shfl_xor(p, 4, 16);
      p += __shfl_xor(p, 8, 16);
      if ((lane & 15) == 0) atomicAdd(&qs[row], p);  // exactly 2 adds/row
    }
  __syncthreads();
  if (tid < 128) ws[fQ + blk * 128 + tid] = qs[tid];
}

// ---------------- K15: out = 2 U V^T - q_i - q_j - log_div (nontemporal) ----------------
__global__ __launch_bounds__(256) void k_pair(const float* __restrict__ ws, float* __restrict__ out) {
  __shared__ float qi[128];
  __shared__ float qj[128];
  __shared__ float sld;
  int bi = blockIdx.x, bj = blockIdx.y, tid = threadIdx.x;
  if (tid < 128) qi[tid] = ws[fQ + bi * 128 + tid];
  else qj[tid - 128] = ws[fQ + bj * 128 + (tid - 128)];
  if (tid == 0) sld = ws[fSCAL + 0];
  __syncthreads();
  int w = tid >> 6, lane = tid & 63;
  int wr = (w >> 1) * 64, wc = (w & 1) * 64;
  const unsigned short* Ubf = (const unsigned short*)(ws + fU);
  const unsigned short* Vbf = (const unsigned short*)(ws + fV);
  f32x4 acc[4][4] = {};
  for (int ks = 0; ks < 4; ks++) {
    int kb = ks * 32 + (lane >> 4) * 8;
    short8 af[4], bfv[4];
    #pragma unroll
    for (int mt = 0; mt < 4; mt++) {
      int r = bi * 128 + wr + mt * 16 + (lane & 15);
      af[mt] = *(const short8*)(Ubf + r * 128 + kb);
    }
    #pragma unroll
    for (int nt = 0; nt < 4; nt++) {
      int c = bj * 128 + wc + nt * 16 + (lane & 15);
      bfv[nt] = *(const short8*)(Vbf + c * 128 + kb);
    }
    #pragma unroll
    for (int mt = 0; mt < 4; mt++)
      #pragma unroll
      for (int nt = 0; nt < 4; nt++)
        acc[mt][nt] = __builtin_amdgcn_mfma_f32_16x16x32_bf16(af[mt], bfv[nt], acc[mt][nt], 0, 0, 0);
  }
  float ld = sld;
  #pragma unroll
  for (int mt = 0; mt < 4; mt++)
    #pragma unroll
    for (int nt = 0; nt < 4; nt++)
      #pragma unroll
      for (int r = 0; r < 4; r++) {
        int row = wr + mt * 16 + (lane >> 4) * 4 + r;
        int col = wc + nt * 16 + (lane & 15);
        float g = acc[mt][nt][r];
        float v = 2.0f * g - qi[row] - qj[col] - ld;
        __builtin_nontemporal_store(v,
          &out[(size_t)(bi * 128 + row) * MTEST + (bj * 128 + col)]);
      }
}

extern "C" void kernel_launch(void* const* d_in, const int* in_sizes, int n_in,
                              void* d_out, int out_size, void* d_ws, size_t ws_size,
                              hipStream_t stream) {
  (void)in_sizes; (void)n_in; (void)out_size; (void)ws_size;
  const float* X = (const float*)d_in[0];
  const float* test = (const float*)d_in[1];
  float* out = (float*)d_out;
  float* ws = (float*)d_ws;

  k_gt_partial<<<64, 256, 0, stream>>>(X, ws);
  k_reduce<<<64, 256, 0, stream>>>(ws);
  k_sbp<<<4, 256, 0, stream>>>(ws);        // SB + P
  k_pows<<<4, 256, 0, stream>>>(ws);       // P2->P3->P4 strips (+trP8)
  k_z<<<4, 256, 0, stream>>>(ws);          // Z
  k_m<<<4, 256, 0, stream>>>(ws);          // M1 strip -> Mm
  k_c2<<<4, 256, 0, stream>>>(ws);         // C2 (+trM4)
  k_xh_t2<<<16, 256, 0, stream>>>(ws);     // XH, T2
  k_t34<<<8, 256, 0, stream>>>(ws);        // T3 | T4
  k_t5g<<<20, 256, 0, stream>>>(ws);       // T5 | G0..G4
  k_thi<<<4, 256, 0, stream>>>(ws);        // T10->T15->T20 strips
  k_bigF<<<4, 256, 0, stream>>>(ws);       // F (+trF2)
  k_b<<<4, 256, 0, stream>>>(ws);          // A1 strip -> Bbf
  k_latent<<<64, 256, 0, stream>>>(test, ws);
  k_pair<<<dim3(64, 64), 256, 0, stream>>>(ws, out);
}

// Round 15
// 245.594 us; speedup vs baseline: 1.1544x; 1.1076x over previous
//
#include <hip/hip_runtime.h>
#include <math.h>

// PLDA pairwise scorer, eigendecomposition-free, all-symmetric formulation.
// Z = S_wn^{-1/2} via degree-4 Chebyshev in P = S_wn - I (elementwise from
// P..P4, interval from tr P^4); M = Z*SB*Z; F = f0(inv_s*M) via degree-19
// base-5 bivariate Chebyshev (F = G0 + T5*G1 + T10*G2 + T15*G3);
// B = (63/64)*inv_s*Z*F*Z.  out = 2 v_i^T B v_j - q_i - q_j - log_div.
// Zero-redundancy strip-chaining (R11 structure, best = 265 us), 15 dispatches,
// 14 serial matmul steps.

#define D 128
#define NCLS 256
#define NPC 64
#define MTEST 8192
#define COUNT (NCLS*NPC)

// ws float-offset layout
#define fMC    0
#define fMEAN  16384
#define fSCAL  16640
#define fMAT   32768
#define fSWRAW 442368
#define fPART  458752
#define fU     458752
#define fV     983040
#define fQ     1507328
#define fBBF   1515520

// matrix slots
#define sP   0
#define sSB  1
#define sP2  2
#define sP3  3
#define sP4  4
#define sZ   5
#define sMm  7
#define sC2  8
#define sXH  10
#define sT2  11
#define sT3  12
#define sT4  13
#define sT5  14
#define sT10 15
#define sT15 16
#define sG0  18   // G0..G3 = 18..21
#define sF   23

using short8 = __attribute__((ext_vector_type(8))) short;
using f32x4  = __attribute__((ext_vector_type(4))) float;

__device__ inline unsigned short f2bf(float f) {
  unsigned u = __float_as_uint(f);
  unsigned r = u + 0x7FFFu + ((u >> 16) & 1u);
  return (unsigned short)(r >> 16);
}
__device__ inline float bf2f(unsigned short h) {
  return __uint_as_float(((unsigned)h) << 16);
}
__device__ inline float valU(const unsigned short* m, int idx) {
  return bf2f(m[idx]) + bf2f(m[idx + 16384]);
}
__device__ inline void storeDual(unsigned short* m, int idx, float g) {
  unsigned short hb = f2bf(g);
  m[idx] = hb;
  m[16384 + idx] = f2bf(g - bf2f(hb));
}
__device__ inline unsigned short* MS(float* ws, int m) {
  return (unsigned short*)(ws + fMAT) + (size_t)m * 32768;
}
// 32-row LDS strip, dual plane (4096-ushort stride), XOR-swizzled rows
__device__ inline short8 st8(const unsigned short* L, int rloc, int colk) {
  unsigned u = ((unsigned)(rloc * 128 + colk)) ^ (((unsigned)(rloc & 7)) << 3);
  return *(const short8*)(L + u);
}
__device__ inline float stValU(const unsigned short* L, int rloc, int col) {
  unsigned u = ((unsigned)(rloc * 128 + col)) ^ (((unsigned)(rloc & 7)) << 3);
  return bf2f(L[u]) + bf2f(L[4096 + u]);
}
__device__ inline void stPutDual(unsigned short* L, int rloc, int col, float g) {
  unsigned u = ((unsigned)(rloc * 128 + col)) ^ (((unsigned)(rloc & 7)) << 3);
  unsigned short hb = f2bf(g);
  L[u] = hb;
  L[4096 + u] = f2bf(g - bf2f(hb));
}

// ---------------- generic strip matmul: C = alpha*(A x B) [+ beta*E1] [+ delta*I]
__device__ float mm_core(const unsigned short* A, const unsigned short* B,
                         unsigned short* C, const unsigned short* E1,
                         float alpha, float beta, float delta, int brow,
                         unsigned short* outBf, float aeff2) {
  int tid = threadIdx.x;
  int w = tid >> 6, lane = tid & 63;
  int wcol = w * 32;
  f32x4 acc[2][2] = {};
  #pragma unroll
  for (int ks = 0; ks < 4; ks++) {
    int kb = ks * 32 + (lane >> 4) * 8;
    short8 ah[2], al[2], bh[2], bl[2];
    #pragma unroll
    for (int mt = 0; mt < 2; mt++) {
      int r = brow + mt * 16 + (lane & 15);
      ah[mt] = *(const short8*)(A + r * 128 + kb);
      al[mt] = *(const short8*)(A + 16384 + r * 128 + kb);
    }
    #pragma unroll
    for (int nt = 0; nt < 2; nt++) {
      int c = wcol + nt * 16 + (lane & 15);
      bh[nt] = *(const short8*)(B + c * 128 + kb);
      bl[nt] = *(const short8*)(B + 16384 + c * 128 + kb);
    }
    #pragma unroll
    for (int mt = 0; mt < 2; mt++)
      #pragma unroll
      for (int nt = 0; nt < 2; nt++) {
        f32x4 a0 = acc[mt][nt];
        a0 = __builtin_amdgcn_mfma_f32_16x16x32_bf16(ah[mt], bh[nt], a0, 0, 0, 0);
        a0 = __builtin_amdgcn_mfma_f32_16x16x32_bf16(al[mt], bh[nt], a0, 0, 0, 0);
        a0 = __builtin_amdgcn_mfma_f32_16x16x32_bf16(ah[mt], bl[nt], a0, 0, 0, 0);
        acc[mt][nt] = a0;
      }
  }
  float tsum = 0.f;
  #pragma unroll
  for (int mt = 0; mt < 2; mt++)
    #pragma unroll
    for (int nt = 0; nt < 2; nt++)
      #pragma unroll
      for (int r = 0; r < 4; r++) {
        int row = brow + mt * 16 + (lane >> 4) * 4 + r;
        int col = wcol + nt * 16 + (lane & 15);
        int idx = row * 128 + col;
        float g = acc[mt][nt][r] * alpha;
        if (E1) g += beta * valU(E1, idx);
        if (row == col) g += delta;
        if (outBf) outBf[idx] = f2bf(g * aeff2);
        else storeDual(C, idx, g);
        tsum += g * g;
      }
  return tsum;
}

// ---------------- K1: Gram partials + class means ----------------
__global__ __launch_bounds__(256) void k_gt_partial(const float* __restrict__ X, float* __restrict__ ws) {
  __shared__ unsigned short xt[128 * 256]; // 64 KB
  int b = blockIdx.x, tid = threadIdx.x;
  const float* Xc = X + b * 256 * D;
  for (int idx = tid; idx < 256 * D; idx += 256) {
    int s = idx >> 7, d = idx & 127;
    unsigned byte = ((unsigned)(d * 512 + s * 2)) ^ (((unsigned)(d & 7)) << 4);
    *(unsigned short*)((char*)xt + byte) = f2bf(Xc[idx]);
  }
  {
    int d = tid & 127;
    for (int cc = (tid >> 7); cc < 4; cc += 2) {
      const float* p = Xc + cc * 64 * D + d;
      float s = 0.f;
      #pragma unroll
      for (int n = 0; n < 64; n++) s += p[n * D];
      ((unsigned short*)ws)[d * 256 + (b * 4 + cc)] = f2bf(s * (1.0f / 64.0f));
    }
  }
  __syncthreads();
  int w = tid >> 6, lane = tid & 63;
  int wr = (w >> 1) * 64, wc = (w & 1) * 64;
  f32x4 acc[4][4] = {};
  for (int ks = 0; ks < 8; ks++) {
    int kb = ks * 32 + (lane >> 4) * 8;
    short8 af[4];
    #pragma unroll
    for (int mt = 0; mt < 4; mt++) {
      int r = wr + mt * 16 + (lane & 15);
      unsigned byte = ((unsigned)(r * 512 + kb * 2)) ^ (((unsigned)(r & 7)) << 4);
      af[mt] = *(short8*)((char*)xt + byte);
    }
    #pragma unroll
    for (int nt = 0; nt < 4; nt++) {
      int c = wc + nt * 16 + (lane & 15);
      unsigned byte = ((unsigned)(c * 512 + kb * 2)) ^ (((unsigned)(c & 7)) << 4);
      short8 bfr = *(short8*)((char*)xt + byte);
      #pragma unroll
      for (int mt = 0; mt < 4; mt++)
        acc[mt][nt] = __builtin_amdgcn_mfma_f32_16x16x32_bf16(af[mt], bfr, acc[mt][nt], 0, 0, 0);
    }
  }
  float* outp = ws + fPART + b * 16384;
  #pragma unroll
  for (int mt = 0; mt < 4; mt++)
    #pragma unroll
    for (int nt = 0; nt < 4; nt++)
      #pragma unroll
      for (int r = 0; r < 4; r++) {
        int row = wr + mt * 16 + (lane >> 4) * 4 + r;
        int col = wc + nt * 16 + (lane & 15);
        outp[row * 128 + col] = acc[mt][nt][r];
      }
}

// ---------------- K2: reduce partials; blk0: mean; blk1: inv_s ----------------
__global__ void k_reduce(float* __restrict__ ws) {
  __shared__ float red2[4];
  int tid = threadIdx.x;
  int idx = blockIdx.x * 256 + tid;
  const float* part = ws + fPART;
  float s = 0.f;
  #pragma unroll 8
  for (int p = 0; p < 64; p++) s += part[p * 16384 + idx];
  ws[fSWRAW + idx] = s;
  if (blockIdx.x == 0 && tid < 128) {
    const unsigned short* McT = (const unsigned short*)ws;
    float m = 0.f;
    for (int k = 0; k < 256; k++) m += bf2f(McT[tid * 256 + k]);
    ws[fMEAN + tid] = m * (1.0f / 256.0f);
  }
  if (blockIdx.x == 1) {
    float v = 0.f;
    if (tid < 128) {
      float gdd = 0.f;
      for (int p = 0; p < 64; p++) gdd += part[p * 16384 + tid * 129];
      const unsigned short* McT = (const unsigned short*)ws;
      float nrm = 0.f;
      for (int k = 0; k < 256; k++) { float x = bf2f(McT[tid * 256 + k]); nrm += x * x; }
      v = gdd * (1.0f / COUNT) - nrm * (1.0f / 256.0f);
    }
    #pragma unroll
    for (int off = 32; off > 0; off >>= 1) v += __shfl_down(v, off);
    if ((tid & 63) == 0) red2[tid >> 6] = v;
    __syncthreads();
    if (tid == 0) {
      float inv_s = 128.0f / (red2[0] + red2[1] + red2[2] + red2[3]);
      ws[fSCAL + 1] = inv_s;
      ws[fSCAL + 7] = 0.984375f * inv_s;
    }
  }
}

// ---------------- K3: SB strip (K=256 MFMA) + P = S_wn - I strip ----------------
__global__ __launch_bounds__(256) void k_sbp(float* __restrict__ ws) {
  const unsigned short* Mc = (const unsigned short*)ws;
  const float* mv = ws + fMEAN;
  const float* swraw = ws + fSWRAW;
  float inv_s = ws[fSCAL + 1];
  unsigned short* SB = MS(ws, sSB);
  unsigned short* P = MS(ws, sP);
  int tid = threadIdx.x, b = blockIdx.x;
  int w = tid >> 6, lane = tid & 63;
  int brow = b * 32, wcol = w * 32;
  f32x4 acc[2][2] = {};
  for (int ks = 0; ks < 8; ks++) {
    int kb = ks * 32 + (lane >> 4) * 8;
    short8 af[2], bfv[2];
    #pragma unroll
    for (int mt = 0; mt < 2; mt++) {
      int r = brow + mt * 16 + (lane & 15);
      af[mt] = *(const short8*)(Mc + r * 256 + kb);
    }
    #pragma unroll
    for (int nt = 0; nt < 2; nt++) {
      int c = wcol + nt * 16 + (lane & 15);
      bfv[nt] = *(const short8*)(Mc + c * 256 + kb);
    }
    #pragma unroll
    for (int mt = 0; mt < 2; mt++)
      #pragma unroll
      for (int nt = 0; nt < 2; nt++)
        acc[mt][nt] = __builtin_amdgcn_mfma_f32_16x16x32_bf16(af[mt], bfv[nt], acc[mt][nt], 0, 0, 0);
  }
  #pragma unroll
  for (int mt = 0; mt < 2; mt++)
    #pragma unroll
    for (int nt = 0; nt < 2; nt++)
      #pragma unroll
      for (int r = 0; r < 4; r++) {
        int row = brow + mt * 16 + (lane >> 4) * 4 + r;
        int col = wcol + nt * 16 + (lane & 15);
        int idx = row * 128 + col;
        float g = acc[mt][nt][r] * (1.0f / 256.0f) - mv[row] * mv[col];
        storeDual(SB, idx, g);
        float s = (swraw[idx] * (1.0f / COUNT) - g - mv[row] * mv[col]) * inv_s;
        storeDual(P, idx, s - ((row == col) ? 1.0f : 0.0f));
      }
}

// ---------------- K4: strips P2 (+tr P^4) -> P3 -> P4 ----------------
__global__ __launch_bounds__(256) void k_pows(float* __restrict__ ws) {
  __shared__ unsigned short sA[8192];
  __shared__ unsigned short sB[8192];
  __shared__ float red[4];
  float* scal = ws + fSCAL;
  const unsigned short* P = MS(ws, sP);
  unsigned short* P2 = MS(ws, sP2);
  unsigned short* P3 = MS(ws, sP3);
  unsigned short* P4 = MS(ws, sP4);
  int tid = threadIdx.x, b = blockIdx.x;
  int w = tid >> 6, lane = tid & 63;
  int brow = b * 32, wcol = w * 32;
  // phase1: P2 strip = P[rows]*P  (+||P2||^2 = trP4 partial)
  float tsum = 0.f;
  {
    f32x4 acc[2][2] = {};
    #pragma unroll
    for (int ks = 0; ks < 4; ks++) {
      int kb = ks * 32 + (lane >> 4) * 8;
      short8 ah[2], al[2], bh[2], bl[2];
      #pragma unroll
      for (int mt = 0; mt < 2; mt++) {
        int r = brow + mt * 16 + (lane & 15);
        ah[mt] = *(const short8*)(P + r * 128 + kb);
        al[mt] = *(const short8*)(P + 16384 + r * 128 + kb);
      }
      #pragma unroll
      for (int nt = 0; nt < 2; nt++) {
        int c = wcol + nt * 16 + (lane & 15);
        bh[nt] = *(const short8*)(P + c * 128 + kb);
        bl[nt] = *(const short8*)(P + 16384 + c * 128 + kb);
      }
      #pragma unroll
      for (int mt = 0; mt < 2; mt++)
        #pragma unroll
        for (int nt = 0; nt < 2; nt++) {
          f32x4 a0 = acc[mt][nt];
          a0 = __builtin_amdgcn_mfma_f32_16x16x32_bf16(ah[mt], bh[nt], a0, 0, 0, 0);
          a0 = __builtin_amdgcn_mfma_f32_16x16x32_bf16(al[mt], bh[nt], a0, 0, 0, 0);
          a0 = __builtin_amdgcn_mfma_f32_16x16x32_bf16(ah[mt], bl[nt], a0, 0, 0, 0);
          acc[mt][nt] = a0;
        }
    }
    #pragma unroll
    for (int mt = 0; mt < 2; mt++)
      #pragma unroll
      for (int nt = 0; nt < 2; nt++)
        #pragma unroll
        for (int r = 0; r < 4; r++) {
          int rloc = mt * 16 + (lane >> 4) * 4 + r;
          int col = wcol + nt * 16 + (lane & 15);
          float g = acc[mt][nt][r];
          stPutDual(sA, rloc, col, g);
          storeDual(P2, (brow + rloc) * 128 + col, g);
          tsum += g * g;
        }
  }
  #pragma unroll
  for (int off = 32; off > 0; off >>= 1) tsum += __shfl_down(tsum, off);
  if (lane == 0) red[w] = tsum;
  __syncthreads();
  if (tid == 0) scal[60 + b] = red[0] + red[1] + red[2] + red[3];
  // phase2: P3 strip = sA*P
  {
    f32x4 acc[2][2] = {};
    #pragma unroll
    for (int ks = 0; ks < 4; ks++) {
      int kb = ks * 32 + (lane >> 4) * 8;
      short8 ah[2], al[2], bh[2], bl[2];
      #pragma unroll
      for (int mt = 0; mt < 2; mt++) {
        int rloc = mt * 16 + (lane & 15);
        ah[mt] = st8(sA, rloc, kb);
        al[mt] = st8(sA + 4096, rloc, kb);
      }
      #pragma unroll
      for (int nt = 0; nt < 2; nt++) {
        int c = wcol + nt * 16 + (lane & 15);
        bh[nt] = *(const short8*)(P + c * 128 + kb);
        bl[nt] = *(const short8*)(P + 16384 + c * 128 + kb);
      }
      #pragma unroll
      for (int mt = 0; mt < 2; mt++)
        #pragma unroll
        for (int nt = 0; nt < 2; nt++) {
          f32x4 a0 = acc[mt][nt];
          a0 = __builtin_amdgcn_mfma_f32_16x16x32_bf16(ah[mt], bh[nt], a0, 0, 0, 0);
          a0 = __builtin_amdgcn_mfma_f32_16x16x32_bf16(al[mt], bh[nt], a0, 0, 0, 0);
          a0 = __builtin_amdgcn_mfma_f32_16x16x32_bf16(ah[mt], bl[nt], a0, 0, 0, 0);
          acc[mt][nt] = a0;
        }
    }
    #pragma unroll
    for (int mt = 0; mt < 2; mt++)
      #pragma unroll
      for (int nt = 0; nt < 2; nt++)
        #pragma unroll
        for (int r = 0; r < 4; r++) {
          int rloc = mt * 16 + (lane >> 4) * 4 + r;
          int col = wcol + nt * 16 + (lane & 15);
          float g = acc[mt][nt][r];
          stPutDual(sB, rloc, col, g);
          storeDual(P3, (brow + rloc) * 128 + col, g);
        }
  }
  __syncthreads();
  // phase3: P4 strip = sB*P
  {
    f32x4 acc[2][2] = {};
    #pragma unroll
    for (int ks = 0; ks < 4; ks++) {
      int kb = ks * 32 + (lane >> 4) * 8;
      short8 ah[2], al[2], bh[2], bl[2];
      #pragma unroll
      for (int mt = 0; mt < 2; mt++) {
        int rloc = mt * 16 + (lane & 15);
        ah[mt] = st8(sB, rloc, kb);
        al[mt] = st8(sB + 4096, rloc, kb);
      }
      #pragma unroll
      for (int nt = 0; nt < 2; nt++) {
        int c = wcol + nt * 16 + (lane & 15);
        bh[nt] = *(const short8*)(P + c * 128 + kb);
        bl[nt] = *(const short8*)(P + 16384 + c * 128 + kb);
      }
      #pragma unroll
      for (int mt = 0; mt < 2; mt++)
        #pragma unroll
        for (int nt = 0; nt < 2; nt++) {
          f32x4 a0 = acc[mt][nt];
          a0 = __builtin_amdgcn_mfma_f32_16x16x32_bf16(ah[mt], bh[nt], a0, 0, 0, 0);
          a0 = __builtin_amdgcn_mfma_f32_16x16x32_bf16(al[mt], bh[nt], a0, 0, 0, 0);
          a0 = __builtin_amdgcn_mfma_f32_16x16x32_bf16(ah[mt], bl[nt], a0, 0, 0, 0);
          acc[mt][nt] = a0;
        }
    }
    #pragma unroll
    for (int mt = 0; mt < 2; mt++)
      #pragma unroll
      for (int nt = 0; nt < 2; nt++)
        #pragma unroll
        for (int r = 0; r < 4; r++) {
          int rloc = mt * 16 + (lane >> 4) * 4 + r;
          int col = wcol + nt * 16 + (lane & 15);
          storeDual(P4, (brow + rloc) * 128 + col, acc[mt][nt][r]);
        }
  }
}

// ---------------- K5: Z = beta0 I + .. + beta4 P^4 (pure elementwise) ----------------
__global__ __launch_bounds__(256) void k_z(float* __restrict__ ws) {
  __shared__ float cj[5];
  __shared__ float bt[5];
  float* scal = ws + fSCAL;
  int tid = threadIdx.x;
  float trP4 = scal[60] + scal[61] + scal[62] + scal[63];
  float a = 1.05f * sqrtf(sqrtf(fmaxf(trP4, 1e-30f)));
  a = fminf(fmaxf(a, 1e-3f), 0.95f);
  if (tid < 5) {
    const float PI = 3.14159265358979f;
    float s = 0.f;
    for (int i = 0; i < 64; i++) {
      float th = (i + 0.5f) * (PI / 64.0f);
      float x = cosf(th);
      s += (1.0f / sqrtf(1.0f + a * x)) * cosf((float)tid * th);
    }
    cj[tid] = s * (2.0f / 64.0f);
  }
  __syncthreads();
  if (tid == 0) {
    float c0h = 0.5f * cj[0];
    float m0 = c0h - cj[2] + cj[4];
    float m1 = cj[1] - 3.0f * cj[3];
    float m2 = 2.0f * cj[2] - 8.0f * cj[4];
    float m3 = 4.0f * cj[3];
    float m4 = 8.0f * cj[4];
    float ia = 1.0f / a, p = 1.f;
    bt[0] = m0;
    p *= ia; bt[1] = m1 * p;
    p *= ia; bt[2] = m2 * p;
    p *= ia; bt[3] = m3 * p;
    p *= ia; bt[4] = m4 * p;
  }
  __syncthreads();
  const unsigned short *P = MS(ws, sP), *P2 = MS(ws, sP2),
    *P3 = MS(ws, sP3), *P4 = MS(ws, sP4);
  unsigned short* Z = MS(ws, sZ);
  float b0 = bt[0], b1 = bt[1], b2 = bt[2], b3 = bt[3], b4 = bt[4];
  int gid = blockIdx.x * 256 + tid;
  #pragma unroll
  for (int t = 0; t < 4; t++) {
    int idx = gid * 4 + t;
    int row = idx >> 7, col = idx & 127;
    float dg = (row == col) ? 1.0f : 0.0f;
    float z = b0 * dg + b1 * valU(P, idx) + b2 * valU(P2, idx) +
              b3 * valU(P3, idx) + b4 * valU(P4, idx);
    storeDual(Z, idx, z);
  }
}

// ---------------- K6: M1 strip (LDS) -> Mm strip ----------------
__global__ __launch_bounds__(256) void k_m(float* __restrict__ ws) {
  __shared__ unsigned short sA[8192];
  const unsigned short* Z = MS(ws, sZ);
  const unsigned short* SB = MS(ws, sSB);
  unsigned short* Mm = MS(ws, sMm);
  int tid = threadIdx.x, b = blockIdx.x;
  int w = tid >> 6, lane = tid & 63;
  int brow = b * 32, wcol = w * 32;
  {
    f32x4 acc[2][2] = {};
    #pragma unroll
    for (int ks = 0; ks < 4; ks++) {
      int kb = ks * 32 + (lane >> 4) * 8;
      short8 ah[2], al[2], bh[2], bl[2];
      #pragma unroll
      for (int mt = 0; mt < 2; mt++) {
        int r = brow + mt * 16 + (lane & 15);
        ah[mt] = *(const short8*)(Z + r * 128 + kb);
        al[mt] = *(const short8*)(Z + 16384 + r * 128 + kb);
      }
      #pragma unroll
      for (int nt = 0; nt < 2; nt++) {
        int c = wcol + nt * 16 + (lane & 15);
        bh[nt] = *(const short8*)(SB + c * 128 + kb);
        bl[nt] = *(const short8*)(SB + 16384 + c * 128 + kb);
      }
      #pragma unroll
      for (int mt = 0; mt < 2; mt++)
        #pragma unroll
        for (int nt = 0; nt < 2; nt++) {
          f32x4 a0 = acc[mt][nt];
          a0 = __builtin_amdgcn_mfma_f32_16x16x32_bf16(ah[mt], bh[nt], a0, 0, 0, 0);
          a0 = __builtin_amdgcn_mfma_f32_16x16x32_bf16(al[mt], bh[nt], a0, 0, 0, 0);
          a0 = __builtin_amdgcn_mfma_f32_16x16x32_bf16(ah[mt], bl[nt], a0, 0, 0, 0);
          acc[mt][nt] = a0;
        }
    }
    #pragma unroll
    for (int mt = 0; mt < 2; mt++)
      #pragma unroll
      for (int nt = 0; nt < 2; nt++)
        #pragma unroll
        for (int r = 0; r < 4; r++) {
          int rloc = mt * 16 + (lane >> 4) * 4 + r;
          int col = wcol + nt * 16 + (lane & 15);
          stPutDual(sA, rloc, col, acc[mt][nt][r]);
        }
  }
  __syncthreads();
  {
    f32x4 acc[2][2] = {};
    #pragma unroll
    for (int ks = 0; ks < 4; ks++) {
      int kb = ks * 32 + (lane >> 4) * 8;
      short8 ah[2], al[2], bh[2], bl[2];
      #pragma unroll
      for (int mt = 0; mt < 2; mt++) {
        int rloc = mt * 16 + (lane & 15);
        ah[mt] = st8(sA, rloc, kb);
        al[mt] = st8(sA + 4096, rloc, kb);
      }
      #pragma unroll
      for (int nt = 0; nt < 2; nt++) {
        int c = wcol + nt * 16 + (lane & 15);
        bh[nt] = *(const short8*)(Z + c * 128 + kb);
        bl[nt] = *(const short8*)(Z + 16384 + c * 128 + kb);
      }
      #pragma unroll
      for (int mt = 0; mt < 2; mt++)
        #pragma unroll
        for (int nt = 0; nt < 2; nt++) {
          f32x4 a0 = acc[mt][nt];
          a0 = __builtin_amdgcn_mfma_f32_16x16x32_bf16(ah[mt], bh[nt], a0, 0, 0, 0);
          a0 = __builtin_amdgcn_mfma_f32_16x16x32_bf16(al[mt], bh[nt], a0, 0, 0, 0);
          a0 = __builtin_amdgcn_mfma_f32_16x16x32_bf16(ah[mt], bl[nt], a0, 0, 0, 0);
          acc[mt][nt] = a0;
        }
    }
    #pragma unroll
    for (int mt = 0; mt < 2; mt++)
      #pragma unroll
      for (int nt = 0; nt < 2; nt++)
        #pragma unroll
        for (int r = 0; r < 4; r++) {
          int rloc = mt * 16 + (lane >> 4) * 4 + r;
          int col = wcol + nt * 16 + (lane & 15);
          storeDual(Mm, (brow + rloc) * 128 + col, acc[mt][nt][r]);
        }
  }
}

// ---------------- K7: C2 strip (+tr M^4 partial) ----------------
__global__ __launch_bounds__(256) void k_c2(float* __restrict__ ws) {
  __shared__ float red[4];
  float* scal = ws + fSCAL;
  const unsigned short* Mm = MS(ws, sMm);
  int tid = threadIdx.x, b = blockIdx.x;
  int w = tid >> 6, lane = tid & 63;
  float tsum = mm_core(Mm, Mm, MS(ws, sC2), nullptr, 1.0f, 0.0f, 0.0f, b * 32, nullptr, 1.0f);
  #pragma unroll
  for (int off = 32; off > 0; off >>= 1) tsum += __shfl_down(tsum, off);
  if (lane == 0) red[w] = tsum;
  __syncthreads();
  if (tid == 0) scal[68 + b] = red[0] + red[1] + red[2] + red[3];
}

// interval from tr M^4 = ||C2||_F^2
__device__ inline void interval_cs(const float* scal, float* c0o, float* iho) {
  float trM4 = scal[68] + scal[69] + scal[70] + scal[71];
  float Lam = 1.03f * sqrtf(sqrtf(fmaxf(trM4, 1e-37f)));
  float lo = -0.02f * Lam, hi = Lam;
  *c0o = 0.5f * (hi + lo);
  *iho = 1.0f / (0.5f * (hi - lo));
}

// ---------------- K8: XH, T2 elementwise ----------------
__global__ __launch_bounds__(256) void k_xh_t2(float* __restrict__ ws) {
  __shared__ float cs[2];
  float* scal = ws + fSCAL;
  if (threadIdx.x == 0) {
    float c0, ih;
    interval_cs(scal, &c0, &ih);
    cs[0] = c0; cs[1] = ih;
  }
  __syncthreads();
  float c0 = cs[0], ih = cs[1];
  float a2 = 2.0f * ih * ih, b2 = -4.0f * c0 * ih * ih, g2 = 2.0f * c0 * c0 * ih * ih - 1.0f;
  const unsigned short* Mm = MS(ws, sMm);
  const unsigned short* C2 = MS(ws, sC2);
  unsigned short* XH = MS(ws, sXH);
  unsigned short* T2 = MS(ws, sT2);
  int gid = blockIdx.x * 256 + threadIdx.x;
  #pragma unroll
  for (int t = 0; t < 4; t++) {
    int idx = gid * 4 + t;
    int row = idx >> 7, col = idx & 127;
    float m = valU(Mm, idx), c2v = valU(C2, idx);
    float dg = (row == col) ? 1.0f : 0.0f;
    storeDual(XH, idx, ih * m - ih * c0 * dg);
    storeDual(T2, idx, a2 * c2v + b2 * m + g2 * dg);
  }
}

// ---------------- K9: T3 = 2 XH T2 - XH (blk 0-3) | T4 = 2 T2^2 - I (blk 4-7) ----------------
__global__ __launch_bounds__(256) void k_t34(float* __restrict__ ws) {
  const unsigned short* XH = MS(ws, sXH);
  const unsigned short* T2 = MS(ws, sT2);
  if (blockIdx.x < 4) {
    mm_core(XH, T2, MS(ws, sT3), XH, 2.0f, -1.0f, 0.0f, blockIdx.x * 32, nullptr, 1.0f);
  } else {
    mm_core(T2, T2, MS(ws, sT4), nullptr, 2.0f, 0.0f, -1.0f, (blockIdx.x - 4) * 32, nullptr, 1.0f);
  }
}

// ---------------- K10: blk 0-3: T5 = 2 T3 T2 - XH; blk 4-19: G0..G3 ----------------
__global__ __launch_bounds__(256) void k_t5g(float* __restrict__ ws) {
  __shared__ float cs[8];
  __shared__ float sat[20];
  __shared__ float sc[20];
  float* scal = ws + fSCAL;
  int tid = threadIdx.x;
  if (blockIdx.x < 4) {
    mm_core(MS(ws, sT3), MS(ws, sT2), MS(ws, sT5), MS(ws, sXH),
            2.0f, -1.0f, 0.0f, blockIdx.x * 32, nullptr, 1.0f);
    return;
  }
  if (tid == 0) {
    float c0, ih;
    interval_cs(scal, &c0, &ih);
    float inv_s = scal[1];
    float t0 = (1.0f / 63.0f) / inv_s;
    float x0 = fminf(fmaxf((t0 - c0) * ih, -1.0f), 1.0f);
    cs[0] = acosf(x0); cs[1] = x0;
    cs[2] = 0.984375f * inv_s / ih;
  }
  __syncthreads();
  if (tid <= 19) {
    float th = cs[0], x0 = cs[1], SCc = cs[2];
    const float PI = 3.14159265358979f;
    float v;
    if (tid == 0) v = 0.5f * SCc * (2.0f / PI) * (sinf(th) - x0 * th);
    else if (tid == 1) v = SCc * (2.0f / PI) * (0.5f * th + 0.25f * sinf(2.0f * th) - x0 * sinf(th));
    else {
      float fj = (float)tid;
      v = SCc * (2.0f / PI) *
          (0.5f * (sinf((fj + 1.0f) * th) / (fj + 1.0f) + sinf((fj - 1.0f) * th) / (fj - 1.0f))
           - x0 * sinf(fj * th) / fj);
    }
    sat[tid] = v;
    sc[tid] = 0.f;
  }
  __syncthreads();
  if (tid == 0) {
    for (int j = 19; j >= 5; --j) {
      int k = j / 5, r = j - 5 * k;
      float aj = sat[j];
      if (r == 0) sc[k * 5] += aj;
      else { sc[k * 5 + r] += 2.0f * aj; sat[5 * k - r] -= aj; }
    }
    for (int r = 0; r < 5; r++) sc[r] += sat[r];
  }
  __syncthreads();
  const unsigned short* XH = MS(ws, sXH);
  const unsigned short* T2 = MS(ws, sT2);
  const unsigned short* T3 = MS(ws, sT3);
  const unsigned short* T4 = MS(ws, sT4);
  int bg = blockIdx.x - 4;
  int base = bg * 1024 + tid * 4;
  #pragma unroll
  for (int t = 0; t < 4; t++) {
    int idx = base + t;
    int row = idx >> 7, col = idx & 127;
    float dg = (row == col) ? 1.0f : 0.0f;
    float x1 = valU(XH, idx), x2 = valU(T2, idx), x3 = valU(T3, idx), x4 = valU(T4, idx);
    #pragma unroll
    for (int k = 0; k < 4; k++) {
      float g = sc[k * 5 + 0] * dg + sc[k * 5 + 1] * x1 + sc[k * 5 + 2] * x2 +
                sc[k * 5 + 3] * x3 + sc[k * 5 + 4] * x4;
      storeDual(MS(ws, sG0 + k), idx, g);
    }
  }
}

// ---------------- K11: strips T10 -> T15 ----------------
__global__ __launch_bounds__(256) void k_thi(float* __restrict__ ws) {
  __shared__ unsigned short sA[8192]; // T10 strip
  const unsigned short* T5 = MS(ws, sT5);
  unsigned short* T10 = MS(ws, sT10);
  unsigned short* T15 = MS(ws, sT15);
  int tid = threadIdx.x, b = blockIdx.x;
  int w = tid >> 6, lane = tid & 63;
  int brow = b * 32, wcol = w * 32;
  // phase1: T10 strip = 2*T5[rows]*T5 - I
  {
    f32x4 acc[2][2] = {};
    #pragma unroll
    for (int ks = 0; ks < 4; ks++) {
      int kb = ks * 32 + (lane >> 4) * 8;
      short8 ah[2], al[2], bh[2], bl[2];
      #pragma unroll
      for (int mt = 0; mt < 2; mt++) {
        int r = brow + mt * 16 + (lane & 15);
        ah[mt] = *(const short8*)(T5 + r * 128 + kb);
        al[mt] = *(const short8*)(T5 + 16384 + r * 128 + kb);
      }
      #pragma unroll
      for (int nt = 0; nt < 2; nt++) {
        int c = wcol + nt * 16 + (lane & 15);
        bh[nt] = *(const short8*)(T5 + c * 128 + kb);
        bl[nt] = *(const short8*)(T5 + 16384 + c * 128 + kb);
      }
      #pragma unroll
      for (int mt = 0; mt < 2; mt++)
        #pragma unroll
        for (int nt = 0; nt < 2; nt++) {
          f32x4 a0 = acc[mt][nt];
          a0 = __builtin_amdgcn_mfma_f32_16x16x32_bf16(ah[mt], bh[nt], a0, 0, 0, 0);
          a0 = __builtin_amdgcn_mfma_f32_16x16x32_bf16(al[mt], bh[nt], a0, 0, 0, 0);
          a0 = __builtin_amdgcn_mfma_f32_16x16x32_bf16(ah[mt], bl[nt], a0, 0, 0, 0);
          acc[mt][nt] = a0;
        }
    }
    #pragma unroll
    for (int mt = 0; mt < 2; mt++)
      #pragma unroll
      for (int nt = 0; nt < 2; nt++)
        #pragma unroll
        for (int r = 0; r < 4; r++) {
          int rloc = mt * 16 + (lane >> 4) * 4 + r;
          int col = wcol + nt * 16 + (lane & 15);
          int row = brow + rloc;
          float g = 2.0f * acc[mt][nt][r] - ((row == col) ? 1.0f : 0.0f);
          stPutDual(sA, rloc, col, g);
          storeDual(T10, row * 128 + col, g);
        }
  }
  __syncthreads();
  // phase2: T15 strip = 2*sA*T5 - T5[rows]
  {
    f32x4 acc[2][2] = {};
    #pragma unroll
    for (int ks = 0; ks < 4; ks++) {
      int kb = ks * 32 + (lane >> 4) * 8;
      short8 ah[2], al[2], bh[2], bl[2];
      #pragma unroll
      for (int mt = 0; mt < 2; mt++) {
        int rloc = mt * 16 + (lane & 15);
        ah[mt] = st8(sA, rloc, kb);
        al[mt] = st8(sA + 4096, rloc, kb);
      }
      #pragma unroll
      for (int nt = 0; nt < 2; nt++) {
        int c = wcol + nt * 16 + (lane & 15);
        bh[nt] = *(const short8*)(T5 + c * 128 + kb);
        bl[nt] = *(const short8*)(T5 + 16384 + c * 128 + kb);
      }
      #pragma unroll
      for (int mt = 0; mt < 2; mt++)
        #pragma unroll
        for (int nt = 0; nt < 2; nt++) {
          f32x4 a0 = acc[mt][nt];
          a0 = __builtin_amdgcn_mfma_f32_16x16x32_bf16(ah[mt], bh[nt], a0, 0, 0, 0);
          a0 = __builtin_amdgcn_mfma_f32_16x16x32_bf16(al[mt], bh[nt], a0, 0, 0, 0);
          a0 = __builtin_amdgcn_mfma_f32_16x16x32_bf16(ah[mt], bl[nt], a0, 0, 0, 0);
          acc[mt][nt] = a0;
        }
    }
    #pragma unroll
    for (int mt = 0; mt < 2; mt++)
      #pragma unroll
      for (int nt = 0; nt < 2; nt++)
        #pragma unroll
        for (int r = 0; r < 4; r++) {
          int rloc = mt * 16 + (lane >> 4) * 4 + r;
          int col = wcol + nt * 16 + (lane & 15);
          int idx = (brow + rloc) * 128 + col;
          storeDual(T15, idx, 2.0f * acc[mt][nt][r] - valU(T5, idx));
        }
  }
}

// ---------------- K12: F = G0 + T5 G1 + T10 G2 + T15 G3 (+trF2) ----------------
__global__ __launch_bounds__(256) void k_bigF(float* __restrict__ ws) {
  __shared__ float red[4];
  float* scal = ws + fSCAL;
  const unsigned short* As[3] = { MS(ws, sT5), MS(ws, sT10), MS(ws, sT15) };
  const unsigned short* Bs[3] = { MS(ws, sG0 + 1), MS(ws, sG0 + 2), MS(ws, sG0 + 3) };
  const unsigned short* G0 = MS(ws, sG0);
  unsigned short* Fm = MS(ws, sF);
  int tid = threadIdx.x, b = blockIdx.x;
  int w = tid >> 6, lane = tid & 63;
  int brow = b * 32, wcol = w * 32;
  f32x4 acc[2][2] = {};
  for (int p = 0; p < 3; p++) {
    const unsigned short* A = As[p];
    const unsigned short* B = Bs[p];
    #pragma unroll
    for (int ks = 0; ks < 4; ks++) {
      int kb = ks * 32 + (lane >> 4) * 8;
      short8 ah[2], al[2], bh[2], bl[2];
      #pragma unroll
      for (int mt = 0; mt < 2; mt++) {
        int r = brow + mt * 16 + (lane & 15);
        ah[mt] = *(const short8*)(A + r * 128 + kb);
        al[mt] = *(const short8*)(A + 16384 + r * 128 + kb);
      }
      #pragma unroll
      for (int nt = 0; nt < 2; nt++) {
        int c = wcol + nt * 16 + (lane & 15);
        bh[nt] = *(const short8*)(B + c * 128 + kb);
        bl[nt] = *(const short8*)(B + 16384 + c * 128 + kb);
      }
      #pragma unroll
      for (int mt = 0; mt < 2; mt++)
        #pragma unroll
        for (int nt = 0; nt < 2; nt++) {
          f32x4 a0 = acc[mt][nt];
          a0 = __builtin_amdgcn_mfma_f32_16x16x32_bf16(ah[mt], bh[nt], a0, 0, 0, 0);
          a0 = __builtin_amdgcn_mfma_f32_16x16x32_bf16(al[mt], bh[nt], a0, 0, 0, 0);
          a0 = __builtin_amdgcn_mfma_f32_16x16x32_bf16(ah[mt], bl[nt], a0, 0, 0, 0);
          acc[mt][nt] = a0;
        }
    }
  }
  float tsum = 0.f;
  #pragma unroll
  for (int mt = 0; mt < 2; mt++)
    #pragma unroll
    for (int nt = 0; nt < 2; nt++)
      #pragma unroll
      for (int r = 0; r < 4; r++) {
        int row = brow + mt * 16 + (lane >> 4) * 4 + r;
        int col = wcol + nt * 16 + (lane & 15);
        int idx = row * 128 + col;
        float g = acc[mt][nt][r] + valU(G0, idx);
        storeDual(Fm, idx, g);
        tsum += g * g;
      }
  #pragma unroll
  for (int off = 32; off > 0; off >>= 1) tsum += __shfl_down(tsum, off);
  if (lane == 0) red[w] = tsum;
  __syncthreads();
  if (tid == 0) scal[72 + b] = red[0] + red[1] + red[2] + red[3];
}

// ---------------- K13: A1 strip (LDS) -> Bbf strip ----------------
__global__ __launch_bounds__(256) void k_b(float* __restrict__ ws) {
  __shared__ unsigned short sA[8192];
  const unsigned short* Z = MS(ws, sZ);
  const unsigned short* Fm = MS(ws, sF);
  unsigned short* Bbf = (unsigned short*)(ws + fBBF);
  float aeff = ws[fSCAL + 7];
  int tid = threadIdx.x, b = blockIdx.x;
  int w = tid >> 6, lane = tid & 63;
  int brow = b * 32, wcol = w * 32;
  {
    f32x4 acc[2][2] = {};
    #pragma unroll
    for (int ks = 0; ks < 4; ks++) {
      int kb = ks * 32 + (lane >> 4) * 8;
      short8 ah[2], al[2], bh[2], bl[2];
      #pragma unroll
      for (int mt = 0; mt < 2; mt++) {
        int r = brow + mt * 16 + (lane & 15);
        ah[mt] = *(const short8*)(Z + r * 128 + kb);
        al[mt] = *(const short8*)(Z + 16384 + r * 128 + kb);
      }
      #pragma unroll
      for (int nt = 0; nt < 2; nt++) {
        int c = wcol + nt * 16 + (lane & 15);
        bh[nt] = *(const short8*)(Fm + c * 128 + kb);
        bl[nt] = *(const short8*)(Fm + 16384 + c * 128 + kb);
      }
      #pragma unroll
      for (int mt = 0; mt < 2; mt++)
        #pragma unroll
        for (int nt = 0; nt < 2; nt++) {
          f32x4 a0 = acc[mt][nt];
          a0 = __builtin_amdgcn_mfma_f32_16x16x32_bf16(ah[mt], bh[nt], a0, 0, 0, 0);
          a0 = __builtin_amdgcn_mfma_f32_16x16x32_bf16(al[mt], bh[nt], a0, 0, 0, 0);
          a0 = __builtin_amdgcn_mfma_f32_16x16x32_bf16(ah[mt], bl[nt], a0, 0, 0, 0);
          acc[mt][nt] = a0;
        }
    }
    #pragma unroll
    for (int mt = 0; mt < 2; mt++)
      #pragma unroll
      for (int nt = 0; nt < 2; nt++)
        #pragma unroll
        for (int r = 0; r < 4; r++) {
          int rloc = mt * 16 + (lane >> 4) * 4 + r;
          int col = wcol + nt * 16 + (lane & 15);
          stPutDual(sA, rloc, col, acc[mt][nt][r]);
        }
  }
  __syncthreads();
  {
    f32x4 acc[2][2] = {};
    #pragma unroll
    for (int ks = 0; ks < 4; ks++) {
      int kb = ks * 32 + (lane >> 4) * 8;
      short8 ah[2], al[2], bh[2], bl[2];
      #pragma unroll
      for (int mt = 0; mt < 2; mt++) {
        int rloc = mt * 16 + (lane & 15);
        ah[mt] = st8(sA, rloc, kb);
        al[mt] = st8(sA + 4096, rloc, kb);
      }
      #pragma unroll
      for (int nt = 0; nt < 2; nt++) {
        int c = wcol + nt * 16 + (lane & 15);
        bh[nt] = *(const short8*)(Z + c * 128 + kb);
        bl[nt] = *(const short8*)(Z + 16384 + c * 128 + kb);
      }
      #pragma unroll
      for (int mt = 0; mt < 2; mt++)
        #pragma unroll
        for (int nt = 0; nt < 2; nt++) {
          f32x4 a0 = acc[mt][nt];
          a0 = __builtin_amdgcn_mfma_f32_16x16x32_bf16(ah[mt], bh[nt], a0, 0, 0, 0);
          a0 = __builtin_amdgcn_mfma_f32_16x16x32_bf16(al[mt], bh[nt], a0, 0, 0, 0);
          a0 = __builtin_amdgcn_mfma_f32_16x16x32_bf16(ah[mt], bl[nt], a0, 0, 0, 0);
          acc[mt][nt] = a0;
        }
    }
    #pragma unroll
    for (int mt = 0; mt < 2; mt++)
      #pragma unroll
      for (int nt = 0; nt < 2; nt++)
        #pragma unroll
        for (int r = 0; r < 4; r++) {
          int rloc = mt * 16 + (lane >> 4) * 4 + r;
          int col = wcol + nt * 16 + (lane & 15);
          Bbf[(brow + rloc) * 128 + col] = f2bf(acc[mt][nt][r] * aeff);
        }
  }
}

// ---------------- K14: V = test - mean; U = V*B; q; blk0: log_div ----------------
__global__ __launch_bounds__(256) void k_latent(const float* __restrict__ test, float* __restrict__ ws) {
  __shared__ unsigned short vh[16384];
  __shared__ float qs[128];
  int blk = blockIdx.x, tid = threadIdx.x;
  if (blk == 0 && tid == 0) {
    float* scal = ws + fSCAL;
    float trF2 = fmaxf(scal[72] + scal[73] + scal[74] + scal[75], 1e-30f);
    scal[0] = 0.5f * (128.0f * 1.8378770664093453f + 0.5f * logf(trF2));
  }
  const float* tb = test + blk * 128 * D;
  unsigned short* Vbf = (unsigned short*)(ws + fV);
  if (tid < 128) qs[tid] = 0.f;
  for (int idx = tid; idx < 16384; idx += 256) {
    int r = idx >> 7, c = idx & 127;
    float v = tb[idx] - ws[fMEAN + c];
    unsigned short h = f2bf(v);
    unsigned byte = ((unsigned)(r * 256 + c * 2)) ^ (((unsigned)(r & 7)) << 4);
    *(unsigned short*)((char*)vh + byte) = h;
    Vbf[blk * 16384 + idx] = h;
  }
  __syncthreads();
  int w = tid >> 6, lane = tid & 63;
  int wr = (w >> 1) * 64, wc = (w & 1) * 64;
  const unsigned short* Bbf = (const unsigned short*)(ws + fBBF);
  f32x4 acc[4][4] = {};
  for (int ks = 0; ks < 4; ks++) {
    int kb = ks * 32 + (lane >> 4) * 8;
    short8 af[4], bfv[4];
    #pragma unroll
    for (int mt = 0; mt < 4; mt++) {
      int r = wr + mt * 16 + (lane & 15);
      unsigned byte = ((unsigned)(r * 256 + kb * 2)) ^ (((unsigned)(r & 7)) << 4);
      af[mt] = *(short8*)((char*)vh + byte);
    }
    #pragma unroll
    for (int nt = 0; nt < 4; nt++) {
      int c = wc + nt * 16 + (lane & 15);
      bfv[nt] = *(const short8*)(Bbf + c * 128 + kb);
    }
    #pragma unroll
    for (int mt = 0; mt < 4; mt++)
      #pragma unroll
      for (int nt = 0; nt < 4; nt++)
        acc[mt][nt] = __builtin_amdgcn_mfma_f32_16x16x32_bf16(af[mt], bfv[nt], acc[mt][nt], 0, 0, 0);
  }
  unsigned short* Ubf = (unsigned short*)(ws + fU);
  #pragma unroll
  for (int mt = 0; mt < 4; mt++)
    #pragma unroll
    for (int nt = 0; nt < 4; nt++)
      #pragma unroll
      for (int r = 0; r < 4; r++) {
        int row = wr + mt * 16 + (lane >> 4) * 4 + r;
        int col = wc + nt * 16 + (lane & 15);
        Ubf[(blk * 128 + row) * 128 + col] = f2bf(acc[mt][nt][r]);
      }
  #pragma unroll
  for (int mt = 0; mt < 4; mt++)
    #pragma unroll
    for (int r = 0; r < 4; r++) {
      int row = wr + mt * 16 + (lane >> 4) * 4 + r;
      float p = 0.f;
      #pragma unroll
      for (int nt = 0; nt < 4; nt++) {
        int col = wc + nt * 16 + (lane & 15);
        unsigned byte = ((unsigned)(row * 256 + col * 2)) ^ (((unsigned)(row & 7)) << 4);
        p += bf2f(f2bf(acc[mt][nt][r])) * bf2f(*(unsigned short*)((char*)vh + byte));
      }
      p += __shfl_xor(p, 1, 16);
      p += __shfl_xor(p, 2, 16);
      p += __shfl_xor(p, 4, 16);
      p += __shfl_xor(p, 8, 16);
      if ((lane & 15) == 0) atomicAdd(&qs[row], p);  // exactly 2 adds/row
    }
  __syncthreads();
  if (tid < 128) ws[fQ + blk * 128 + tid] = qs[tid];
}

// ---------------- K15: out = 2 U V^T - q_i - q_j - log_div ----------------
__global__ __launch_bounds__(256) void k_pair(const float* __restrict__ ws, float* __restrict__ out) {
  __shared__ float qi[128];
  __shared__ float qj[128];
  __shared__ float sld;
  int bi = blockIdx.x, bj = blockIdx.y, tid = threadIdx.x;
  if (tid < 128) qi[tid] = ws[fQ + bi * 128 + tid];
  else qj[tid - 128] = ws[fQ + bj * 128 + (tid - 128)];
  if (tid == 0) sld = ws[fSCAL + 0];
  __syncthreads();
  int w = tid >> 6, lane = tid & 63;
  int wr = (w >> 1) * 64, wc = (w & 1) * 64;
  const unsigned short* Ubf = (const unsigned short*)(ws + fU);
  const unsigned short* Vbf = (const unsigned short*)(ws + fV);
  f32x4 acc[4][4] = {};
  for (int ks = 0; ks < 4; ks++) {
    int kb = ks * 32 + (lane >> 4) * 8;
    short8 af[4], bfv[4];
    #pragma unroll
    for (int mt = 0; mt < 4; mt++) {
      int r = bi * 128 + wr + mt * 16 + (lane & 15);
      af[mt] = *(const short8*)(Ubf + r * 128 + kb);
    }
    #pragma unroll
    for (int nt = 0; nt < 4; nt++) {
      int c = bj * 128 + wc + nt * 16 + (lane & 15);
      bfv[nt] = *(const short8*)(Vbf + c * 128 + kb);
    }
    #pragma unroll
    for (int mt = 0; mt < 4; mt++)
      #pragma unroll
      for (int nt = 0; nt < 4; nt++)
        acc[mt][nt] = __builtin_amdgcn_mfma_f32_16x16x32_bf16(af[mt], bfv[nt], acc[mt][nt], 0, 0, 0);
  }
  float ld = sld;
  #pragma unroll
  for (int mt = 0; mt < 4; mt++)
    #pragma unroll
    for (int nt = 0; nt < 4; nt++)
      #pragma unroll
      for (int r = 0; r < 4; r++) {
        int row = wr + mt * 16 + (lane >> 4) * 4 + r;
        int col = wc + nt * 16 + (lane & 15);
        float g = acc[mt][nt][r];
        out[(size_t)(bi * 128 + row) * MTEST + (bj * 128 + col)] =
          2.0f * g - qi[row] - qj[col] - ld;
      }
}

extern "C" void kernel_launch(void* const* d_in, const int* in_sizes, int n_in,
                              void* d_out, int out_size, void* d_ws, size_t ws_size,
                              hipStream_t stream) {
  (void)in_sizes; (void)n_in; (void)out_size; (void)ws_size;
  const float* X = (const float*)d_in[0];
  const float* test = (const float*)d_in[1];
  float* out = (float*)d_out;
  float* ws = (float*)d_ws;

  k_gt_partial<<<64, 256, 0, stream>>>(X, ws);
  k_reduce<<<64, 256, 0, stream>>>(ws);
  k_sbp<<<4, 256, 0, stream>>>(ws);        // SB + P
  k_pows<<<4, 256, 0, stream>>>(ws);       // P2 (+trP4) -> P3 -> P4
  k_z<<<16, 256, 0, stream>>>(ws);         // Z (elementwise, deg-4)
  k_m<<<4, 256, 0, stream>>>(ws);          // M1 strip -> Mm
  k_c2<<<4, 256, 0, stream>>>(ws);         // C2 (+trM4)
  k_xh_t2<<<16, 256, 0, stream>>>(ws);     // XH, T2
  k_t34<<<8, 256, 0, stream>>>(ws);        // T3 | T4
  k_t5g<<<20, 256, 0, stream>>>(ws);       // T5 | G0..G3
  k_thi<<<4, 256, 0, stream>>>(ws);        // T10 -> T15 strips
  k_bigF<<<4, 256, 0, stream>>>(ws);       // F (+trF2)
  k_b<<<4, 256, 0, stream>>>(ws);          // A1 strip -> Bbf
  k_latent<<<64, 256, 0, stream>>>(test, ws);
  k_pair<<<dim3(64, 64), 256, 0, stream>>>(ws, out);
}